// Round 13
// baseline (1216.081 us; speedup 1.0000x reference)
//
#include <hip/hip_runtime.h>
#include <cstdint>

typedef unsigned short u16;
typedef __attribute__((ext_vector_type(8))) __bf16 bf16x8;
typedef __attribute__((ext_vector_type(4))) float f32x4;

#define TOK 4096
#define DM  1024
#define EXP 8
#define FF  4096
#define SEQ 512
#define NH  8
#define HD  128
#define JOBCAP 18432

__device__ __forceinline__ u16 f2bf(float f) {
  union { float f; unsigned int u; } v; v.f = f;
  unsigned int u = v.u;
  u += 0x7FFFu + ((u >> 16) & 1u);   // round-to-nearest-even
  return (u16)(u >> 16);
}
__device__ __forceinline__ float bf2f(u16 h) {
  union { unsigned int u; float f; } v; v.u = ((unsigned int)h) << 16; return v.f;
}

// async global->LDS, 16B per lane; dest = wave-uniform base + lane*16
__device__ __forceinline__ void gl_lds16(const u16* g, u16* l) {
  __builtin_amdgcn_global_load_lds(
      (const __attribute__((address_space(1))) unsigned int*)g,
      (__attribute__((address_space(3))) unsigned int*)l, 16, 0, 0);
}

// ---------------- embed gather ----------------
__global__ void k_embed(const int* __restrict__ ids, const float* __restrict__ emb,
                        float* __restrict__ x) {
  int t = blockIdx.x;
  int id = ids[t];
  const float4* src = (const float4*)(emb + (size_t)id * DM);
  float4* dst = (float4*)(x + (size_t)t * DM);
  dst[threadIdx.x] = src[threadIdx.x];
}

// ---------------- fused layernorm(bf16 out) + router (MoE path) ----------------
__global__ void k_lnrouter(const float* __restrict__ xin, const float* __restrict__ g,
                           const float* __restrict__ be,
                           const float* __restrict__ Wr, const float* __restrict__ br,
                           const float* __restrict__ Wn, const float* __restrict__ bn,
                           const float* __restrict__ noise,
                           u16* __restrict__ obf,
                           float* __restrict__ gates, int* __restrict__ topidx) {
  int t = blockIdx.x, tid = threadIdx.x;
  float4 v = ((const float4*)(xin + (size_t)t * DM))[tid];
  float s = v.x + v.y + v.z + v.w;
  float sq = v.x*v.x + v.y*v.y + v.z*v.z + v.w*v.w;
  for (int o = 32; o; o >>= 1) { s += __shfl_down(s, o); sq += __shfl_down(sq, o); }
  __shared__ float ss[4], sqs[4];
  if ((tid & 63) == 0) { ss[tid >> 6] = s; sqs[tid >> 6] = sq; }
  __syncthreads();
  s  = ss[0] + ss[1] + ss[2] + ss[3];
  sq = sqs[0] + sqs[1] + sqs[2] + sqs[3];
  float mean = s * (1.f / DM);
  float var  = sq * (1.f / DM) - mean * mean;
  float rstd = rsqrtf(var + 1e-5f);
  float4 gg = ((const float4*)g)[tid];
  float4 bb = ((const float4*)be)[tid];
  float xl[4];
  xl[0] = (v.x - mean) * rstd * gg.x + bb.x;
  xl[1] = (v.y - mean) * rstd * gg.y + bb.y;
  xl[2] = (v.z - mean) * rstd * gg.z + bb.z;
  xl[3] = (v.w - mean) * rstd * gg.w + bb.w;
  ushort4 u;
  u.x = f2bf(xl[0]); u.y = f2bf(xl[1]); u.z = f2bf(xl[2]); u.w = f2bf(xl[3]);
  ((ushort4*)(obf + (size_t)t * DM))[tid] = u;

  float pl[8], pn[8];
  #pragma unroll
  for (int e = 0; e < 8; e++) { pl[e] = 0.f; pn[e] = 0.f; }
  #pragma unroll
  for (int j = 0; j < 4; j++) {
    int d = tid * 4 + j;
    float xv = xl[j];
    const float4* wr = (const float4*)(Wr + (size_t)d * 8);
    const float4* wn = (const float4*)(Wn + (size_t)d * 8);
    float4 a0 = wr[0], a1 = wr[1], c0 = wn[0], c1 = wn[1];
    pl[0] += xv * a0.x; pl[1] += xv * a0.y; pl[2] += xv * a0.z; pl[3] += xv * a0.w;
    pl[4] += xv * a1.x; pl[5] += xv * a1.y; pl[6] += xv * a1.z; pl[7] += xv * a1.w;
    pn[0] += xv * c0.x; pn[1] += xv * c0.y; pn[2] += xv * c0.z; pn[3] += xv * c0.w;
    pn[4] += xv * c1.x; pn[5] += xv * c1.y; pn[6] += xv * c1.z; pn[7] += xv * c1.w;
  }
  for (int o = 32; o; o >>= 1) {
    #pragma unroll
    for (int e = 0; e < 8; e++) { pl[e] += __shfl_down(pl[e], o); pn[e] += __shfl_down(pn[e], o); }
  }
  __shared__ float sl[4][8], sn[4][8];
  if ((tid & 63) == 0) {
    int w = tid >> 6;
    #pragma unroll
    for (int e = 0; e < 8; e++) { sl[w][e] = pl[e]; sn[w][e] = pn[e]; }
  }
  __syncthreads();
  if (tid == 0) {
    float noisy[8];
    #pragma unroll
    for (int e = 0; e < 8; e++) {
      float l  = sl[0][e] + sl[1][e] + sl[2][e] + sl[3][e] + br[e];
      float nn = sn[0][e] + sn[1][e] + sn[2][e] + sn[3][e] + bn[e];
      float sp = (nn > 20.f) ? nn : log1pf(expf(nn));
      noisy[e] = l + noise[(size_t)t * 8 + e] * sp;
    }
    int i0 = 0;
    for (int e = 1; e < 8; e++) if (noisy[e] > noisy[i0]) i0 = e;
    int i1 = (i0 == 0) ? 1 : 0;
    for (int e = 0; e < 8; e++) if (e != i0 && noisy[e] > noisy[i1]) i1 = e;
    float e1 = expf(noisy[i1] - noisy[i0]);
    float zz = 1.f + e1;
    gates[t * 2] = 1.f / zz; gates[t * 2 + 1] = e1 / zz;
    topidx[t * 2] = i0; topidx[t * 2 + 1] = i1;
  }
}

// ---------------- layernorm -> hi/lo bf16 pair (attention path) ----------------
__global__ void k_ln2(const float* __restrict__ in, const float* __restrict__ g,
                      const float* __restrict__ be, u16* __restrict__ oh,
                      u16* __restrict__ ol) {
  int t = blockIdx.x, tid = threadIdx.x;
  float4 v = ((const float4*)(in + (size_t)t * DM))[tid];
  float s = v.x + v.y + v.z + v.w;
  float sq = v.x*v.x + v.y*v.y + v.z*v.z + v.w*v.w;
  for (int o = 32; o; o >>= 1) { s += __shfl_down(s, o); sq += __shfl_down(sq, o); }
  __shared__ float ss[4], sqs[4];
  if ((tid & 63) == 0) { ss[tid >> 6] = s; sqs[tid >> 6] = sq; }
  __syncthreads();
  s  = ss[0] + ss[1] + ss[2] + ss[3];
  sq = sqs[0] + sqs[1] + sqs[2] + sqs[3];
  float mean = s * (1.f / DM);
  float var  = sq * (1.f / DM) - mean * mean;
  float rstd = rsqrtf(var + 1e-5f);
  float4 gg = ((const float4*)g)[tid];
  float4 bb = ((const float4*)be)[tid];
  float o4[4];
  o4[0] = (v.x - mean) * rstd * gg.x + bb.x;
  o4[1] = (v.y - mean) * rstd * gg.y + bb.y;
  o4[2] = (v.z - mean) * rstd * gg.z + bb.z;
  o4[3] = (v.w - mean) * rstd * gg.w + bb.w;
  ushort4 uh, ul;
  u16* ph = (u16*)&uh; u16* pl = (u16*)&ul;
  #pragma unroll
  for (int i = 0; i < 4; i++) {
    u16 hi = f2bf(o4[i]); ph[i] = hi; pl[i] = f2bf(o4[i] - bf2f(hi));
  }
  ((ushort4*)(oh + (size_t)t * DM))[tid] = uh;
  ((ushort4*)(ol + (size_t)t * DM))[tid] = ul;
}

// ---------------- transpose f32 [1024,1024] -> hi/lo bf16, 4 weights batched ----------------
__global__ void k_tcvt_split4(const float* __restrict__ Wq, const float* __restrict__ Wk,
                              const float* __restrict__ Wv, const float* __restrict__ Wo,
                              u16* __restrict__ qkvh, u16* __restrict__ qkvl,
                              u16* __restrict__ oh, u16* __restrict__ ol) {
  __shared__ float t[32][33];
  int z = blockIdx.z;
  const float* src = (z == 0) ? Wq : (z == 1) ? Wk : (z == 2) ? Wv : Wo;
  u16* dh = (z < 3) ? qkvh + (size_t)z * DM * DM : oh;
  u16* dl = (z < 3) ? qkvl + (size_t)z * DM * DM : ol;
  int k0 = blockIdx.x * 32, n0 = blockIdx.y * 32;
  int tx = threadIdx.x, ty = threadIdx.y;
  #pragma unroll
  for (int i = 0; i < 4; i++) t[ty + 8*i][tx] = src[(size_t)(k0 + ty + 8*i) * DM + n0 + tx];
  __syncthreads();
  int u = ty * 32 + tx;
  int r = u >> 3, kq = u & 7;
  ushort4 ohv, olv;
  u16* ph = (u16*)&ohv; u16* pl = (u16*)&olv;
  #pragma unroll
  for (int i = 0; i < 4; i++) {
    float v = t[kq*4+i][r];
    u16 hi = f2bf(v); ph[i] = hi; pl[i] = f2bf(v - bf2f(hi));
  }
  *(ushort4*)&dh[(size_t)(n0 + r) * DM + k0 + kq*4] = ohv;
  *(ushort4*)&dl[(size_t)(n0 + r) * DM + k0 + kq*4] = olv;
}

// ---------------- transpose f32 [K,N] -> bf16 [N,K], 64x64 tiles, 16-expert dual-source ----------------
__global__ void k_tcvt64(const float* __restrict__ srcA, const float* __restrict__ srcB,
                         u16* __restrict__ dst, int K, int N) {
  __shared__ float t[64][65];
  int z = blockIdx.z;
  const float* src = (z < 8) ? srcA + (size_t)z * K * N : srcB + (size_t)(z - 8) * K * N;
  u16* d = dst + (size_t)z * K * N;
  int k0 = blockIdx.x * 64, n0 = blockIdx.y * 64;
  int u = threadIdx.y * 32 + threadIdx.x;
  #pragma unroll
  for (int i = 0; i < 4; i++) {
    int idx = u + i * 256;
    int kr = idx >> 4, nq = (idx & 15) * 4;
    float4 v = *(const float4*)&src[(size_t)(k0 + kr) * N + n0 + nq];
    t[kr][nq] = v.x; t[kr][nq+1] = v.y; t[kr][nq+2] = v.z; t[kr][nq+3] = v.w;
  }
  __syncthreads();
  #pragma unroll
  for (int j = 0; j < 2; j++) {
    int idx = u + j * 256;
    int nr = idx >> 3, kq = (idx & 7) * 8;
    ushort4 o0, o1;
    u16* p0 = (u16*)&o0; u16* p1 = (u16*)&o1;
    #pragma unroll
    for (int i = 0; i < 4; i++) p0[i] = f2bf(t[kq + i][nr]);
    #pragma unroll
    for (int i = 0; i < 4; i++) p1[i] = f2bf(t[kq + 4 + i][nr]);
    *(ushort4*)&d[(size_t)(n0 + nr) * K + k0 + kq]     = o0;
    *(ushort4*)&d[(size_t)(n0 + nr) * K + k0 + kq + 4] = o1;
  }
}

// ---------------- causal softmax f32 -> att hi/lo bf16 in place ----------------
__global__ void k_softmax_h(float* __restrict__ scores) {
  int q = blockIdx.x, bh = blockIdx.y, tid = threadIdx.x;
  float* row = scores + ((size_t)bh * 512 + q) * 512;
  u16* orow = (u16*)row;
  const float scale = 0.088388347648318447f; // 128^-0.5
  int j0 = tid * 2;
  float v0 = -1e30f, v1 = -1e30f;
  if (j0 <= q)     v0 = row[j0] * scale;
  if (j0 + 1 <= q) v1 = row[j0 + 1] * scale;
  float m = fmaxf(v0, v1);
  for (int o = 32; o; o >>= 1) m = fmaxf(m, __shfl_down(m, o));
  __shared__ float sm[4], ssum[4];
  if ((tid & 63) == 0) sm[tid >> 6] = m;
  __syncthreads();
  m = fmaxf(fmaxf(sm[0], sm[1]), fmaxf(sm[2], sm[3]));
  float p0 = (j0 <= q)     ? expf(v0 - m) : 0.f;
  float p1 = (j0 + 1 <= q) ? expf(v1 - m) : 0.f;
  float s = p0 + p1;
  for (int o = 32; o; o >>= 1) s += __shfl_down(s, o);
  if ((tid & 63) == 0) ssum[tid >> 6] = s;
  __syncthreads();
  s = ssum[0] + ssum[1] + ssum[2] + ssum[3];
  float inv = 1.f / s;
  float pi0 = p0 * inv, pi1 = p1 * inv;
  u16 h0 = f2bf(pi0), h1 = f2bf(pi1);
  orow[j0]       = h0; orow[j0 + 1]       = h1;
  orow[512 + j0] = f2bf(pi0 - bf2f(h0));
  orow[512 + j0 + 1] = f2bf(pi1 - bf2f(h1));
}

// ---------------- split-bf16 3-pass MFMA GEMM (attention path) ----------------
constexpr int HOP_QKV    = 0;
constexpr int HOP_SCORES = 1;
constexpr int HOP_PV     = 2;
constexpr int HOP_PROJ   = 3;

struct GemmHArgs {
  const u16 *Ah, *Al, *Bh, *Bl;
  u16 *D0h, *D0l, *D1h, *D1l, *D2h, *D2l;
  float *Cf;
  const float *bias, *resid, *pos;
  int lda, ldb, K;
};

template<int OP>
__launch_bounds__(256)
__global__ void gemm_h(GemmHArgs p) {
  int bx, by, z;
  if constexpr (OP == HOP_QKV) {
    int bid = blockIdx.x; int xcd = bid & 7, slot = bid >> 3;
    by = xcd * 3 + (slot >> 5); bx = slot & 31; z = 0;
  } else if constexpr (OP == HOP_PROJ) {
    int bid = blockIdx.x; by = bid & 7; bx = bid >> 3; z = 0;
  } else if constexpr (OP == HOP_SCORES) { // dense triangular: 10 tiles x 64 bh
    int bid = blockIdx.x; z = bid / 10; int t = bid % 10;
    bx = (t >= 6) ? 3 : (t >= 3) ? 2 : (t >= 1) ? 1 : 0;
    by = t - ((bx * (bx + 1)) >> 1);
  } else {
    bx = blockIdx.x; by = blockIdx.y; z = blockIdx.z;
  }

  const u16 *Ahb, *Alb, *Bhb, *Blb;
  if constexpr (OP == HOP_SCORES) {
    size_t off = (size_t)(z >> 3) * 524288 + (size_t)(z & 7) * 128;
    Ahb = p.Ah + off; Alb = p.Al + off; Bhb = p.Bh + off; Blb = p.Bl + off;
  } else if constexpr (OP == HOP_PV) {
    size_t aoff = (size_t)z * 524288;
    Ahb = p.Ah + aoff; Alb = p.Ah + aoff + 512;
    size_t boff = (size_t)z * 65536;
    Bhb = p.Bh + boff; Blb = p.Bl + boff;
  } else {
    Ahb = p.Ah; Alb = p.Al; Bhb = p.Bh; Blb = p.Bl;
  }

  int kmax = p.K;
  if constexpr (OP == HOP_PV) { int lim = bx * 128 + 128; kmax = lim < p.K ? lim : p.K; }
  int nt = kmax >> 5;

  __shared__ __align__(16) u16 As[2 * 4096];
  __shared__ __align__(16) u16 Bs[2 * 4096];

  int tid = threadIdx.x, lane = tid & 63, wid = tid >> 6;
  int srow = wid * 16 + (lane >> 2), skoff = (lane & 3) * 8;
  int lo0 = (wid * 16) * 32, lo1 = ((wid + 4) * 16) * 32;
  int wr = wid >> 1, wc = wid & 1, fm = lane & 15, fk = (lane >> 4) * 8;

  f32x4 acc[4][4] = {};
  const size_t lda = p.lda, ldb = p.ldb;

  #pragma unroll 1
  for (int pass = 0; pass < 3; ++pass) {
    const u16* Ab = (pass < 2) ? Ahb : Alb;
    const u16* Bb = (pass & 1) ? Blb : Bhb;
    const u16* aptr0 = Ab + (size_t)(bx * 128 + srow) * lda + skoff;
    const u16* aptr1 = Ab + (size_t)(bx * 128 + 64 + srow) * lda + skoff;
    const u16* bptr0 = Bb + (size_t)(by * 128 + srow) * ldb + skoff;
    const u16* bptr1 = Bb + (size_t)(by * 128 + 64 + srow) * ldb + skoff;

    gl_lds16(aptr0, &As[lo0]); gl_lds16(aptr1, &As[lo1]);
    gl_lds16(bptr0, &Bs[lo0]); gl_lds16(bptr1, &Bs[lo1]);
    __syncthreads();
    int cur = 0;
    for (int t = 0; t < nt; ++t) {
      if (t + 1 < nt) {
        int nxt = (cur ^ 1) * 4096;
        int k0 = (t + 1) * 32;
        gl_lds16(aptr0 + k0, &As[nxt + lo0]); gl_lds16(aptr1 + k0, &As[nxt + lo1]);
        gl_lds16(bptr0 + k0, &Bs[nxt + lo0]); gl_lds16(bptr1 + k0, &Bs[nxt + lo1]);
      }
      int cb = cur * 4096;
      bf16x8 af[4], bfr[4];
      #pragma unroll
      for (int i = 0; i < 4; ++i) {
        af[i]  = *(const bf16x8*)&As[cb + (wr * 64 + i * 16 + fm) * 32 + fk];
        bfr[i] = *(const bf16x8*)&Bs[cb + (wc * 64 + i * 16 + fm) * 32 + fk];
      }
      #pragma unroll
      for (int mi = 0; mi < 4; ++mi)
        #pragma unroll
        for (int ni = 0; ni < 4; ++ni)
          acc[mi][ni] = __builtin_amdgcn_mfma_f32_16x16x32_bf16(af[mi], bfr[ni], acc[mi][ni], 0, 0, 0);
      __syncthreads();
      cur ^= 1;
    }
  }

  int rb = (lane >> 4) * 4, cl = lane & 15;
  #pragma unroll
  for (int mi = 0; mi < 4; ++mi)
    #pragma unroll
    for (int ni = 0; ni < 4; ++ni)
      #pragma unroll
      for (int j = 0; j < 4; ++j) {
        int m = bx * 128 + wr * 64 + mi * 16 + rb + j;
        int n = by * 128 + wc * 64 + ni * 16 + cl;
        float v = acc[mi][ni][j];
        if constexpr (OP == HOP_QKV) {
          u16 hi = f2bf(v); u16 lo = f2bf(v - bf2f(hi));
          int sel = n >> 10, nn = n & 1023;
          if (sel == 0) {
            p.D0h[(size_t)m * DM + nn] = hi; p.D0l[(size_t)m * DM + nn] = lo;
          } else if (sel == 1) {
            p.D1h[(size_t)m * DM + nn] = hi; p.D1l[(size_t)m * DM + nn] = lo;
          } else {
            size_t idx = (size_t)((m >> 9) * 8 + (nn >> 7)) * 65536 + (size_t)(nn & 127) * 512 + (m & 511);
            p.D2h[idx] = hi; p.D2l[idx] = lo;
          }
        } else if constexpr (OP == HOP_SCORES) {
          p.Cf[(size_t)z * 262144 + (size_t)m * 512 + n] = v;
        } else if constexpr (OP == HOP_PV) {
          u16 hi = f2bf(v); u16 lo = f2bf(v - bf2f(hi));
          size_t idx = (size_t)(z >> 3) * 524288 + (size_t)m * 1024 + (size_t)(z & 7) * 128 + n;
          p.D0h[idx] = hi; p.D0l[idx] = lo;
        } else { // HOP_PROJ
          size_t idx = (size_t)m * 1024 + n;
          p.Cf[idx] = v + p.bias[n] + p.resid[idx] + p.pos[(size_t)(m & 511) * 1024 + n];
        }
      }
}

// ---------------- bf16 MFMA 128x128 TN GEMM, BK=64 2-phase dbuf + XOR swizzle (MoE) ----------------
// LDS rows are 64 u16 (128B); both-sides swizzle: global source col quad
// ((lane&7)^(lane>>3)), read back at quad (q ^ (fm&7)) -> 2 lanes/bank (free).
constexpr int OP_MOE1 = 0; // gathered A rows (joblist -> xlnb[2*TOK]), bf16 C=relu(acc+b1)
constexpr int OP_MOE2 = 1; // contiguous padded A rows, f32 C=acc+b2

struct GemmArgs {
  const u16* A; const u16* B; void* C;
  const float* b1a; const float* b1b;   // per-half bias arrays (8 experts each)
  const int* joblist; const int* seg;   // seg[0..16]
  int lda, ldb, K;
};

template<int OP>
__launch_bounds__(256)
__global__ void gemm_k(GemmArgs p) {
  int bid = blockIdx.x;
  int xcd = bid & 7, slot = bid >> 3;
  int bx, by;
  if constexpr (OP == OP_MOE1) {
    by = xcd * 4 + (slot & 3);        // grid 4608
    bx = slot >> 2;
  } else {
    bx = xcd * 18 + (slot >> 3);      // grid 1152
    by = slot & 7;
  }
  int r0g = bx * 128;
  if (r0g >= p.seg[16]) return;
  int z = 0;
  #pragma unroll
  for (int e = 1; e < 16; ++e) z += (r0g >= p.seg[e]) ? 1 : 0;
  const u16* Bbase = p.B + (size_t)z * 4194304;
  const float* bias = (z < 8) ? p.b1a + (size_t)z * (OP == OP_MOE1 ? FF : DM)
                              : p.b1b + (size_t)(z - 8) * (OP == OP_MOE1 ? FF : DM);

  __shared__ __align__(16) u16 As[2 * 8192];   // [buf][128][64]
  __shared__ __align__(16) u16 Bs[2 * 8192];

  int tid = threadIdx.x;
  int lane = tid & 63, wid = tid >> 6;

  // staging: wave w covers rows [w*32, w*32+32) as 4 chunks of 8 rows.
  // lane l -> chunk-row (l>>3), source col quad swizzled: ((l&7)^(l>>3))*8
  int lr = lane >> 3;                       // row within chunk & row&7 of LDS row
  int skq = (((lane & 7) ^ lr) * 8);        // pre-swizzled source col (u16)

  const u16 *aptr[4], *bptr[4];
  #pragma unroll
  for (int c = 0; c < 4; ++c) {
    int row = wid * 32 + c * 8 + lr;
    if constexpr (OP == OP_MOE1) {
      int j = p.joblist[r0g + row];
      aptr[c] = p.A + (size_t)(j < 0 ? 0 : j) * p.lda + skq;
    } else {
      aptr[c] = p.A + (size_t)(r0g + row) * p.lda + skq;
    }
    bptr[c] = Bbase + (size_t)(by * 128 + row) * p.ldb + skq;
  }
  int lbase = wid * 2048;                   // wave LDS base (u16), chunk c at +c*512

  int wr = wid >> 1, wc = wid & 1;
  int fm = lane & 15;
  int hi = lane >> 4;
  int f7 = fm & 7;

  f32x4 acc[4][4] = {};
  int nt = p.K >> 6;

#define STAGE(BUF, K0) {                                                     \
    u16* a_ = &As[(BUF) * 8192 + lbase]; u16* b_ = &Bs[(BUF) * 8192 + lbase];\
    _Pragma("unroll") for (int c = 0; c < 4; ++c) {                          \
      gl_lds16(aptr[c] + (K0), a_ + c * 512);                                \
      gl_lds16(bptr[c] + (K0), b_ + c * 512);                                \
    } }

  STAGE(0, 0);
  __syncthreads();

  int cur = 0;
  for (int t = 0; t < nt; ++t) {
    if (t + 1 < nt) STAGE(cur ^ 1, (t + 1) * 64);
    int cb = cur * 8192;
    #pragma unroll
    for (int ks = 0; ks < 2; ++ks) {
      int q = ((ks * 4 + hi) ^ f7) * 8;     // swizzled read quad offset
      bf16x8 af[4], bfr[4];
      #pragma unroll
      for (int i = 0; i < 4; ++i) {
        af[i]  = *(const bf16x8*)&As[cb + (wr * 64 + i * 16 + fm) * 64 + q];
        bfr[i] = *(const bf16x8*)&Bs[cb + (wc * 64 + i * 16 + fm) * 64 + q];
      }
      #pragma unroll
      for (int mi = 0; mi < 4; ++mi)
        #pragma unroll
        for (int ni = 0; ni < 4; ++ni)
          acc[mi][ni] = __builtin_amdgcn_mfma_f32_16x16x32_bf16(af[mi], bfr[ni], acc[mi][ni], 0, 0, 0);
    }
    __syncthreads();
    cur ^= 1;
  }
#undef STAGE

  int rb = (lane >> 4) * 4;
  int cl = lane & 15;
  #pragma unroll
  for (int mi = 0; mi < 4; ++mi)
    #pragma unroll
    for (int ni = 0; ni < 4; ++ni)
      #pragma unroll
      for (int j = 0; j < 4; ++j) {
        int m = r0g + wr * 64 + mi * 16 + rb + j;
        int n = by * 128 + wc * 64 + ni * 16 + cl;
        float v = acc[mi][ni][j];
        if constexpr (OP == OP_MOE1) {
          float t2 = v + bias[n];
          t2 = t2 > 0.f ? t2 : 0.f;
          ((u16*)p.C)[(size_t)m * FF + n] = f2bf(t2);
        } else {
          ((float*)p.C)[(size_t)m * DM + n] = v + bias[n];
        }
      }
}

// ---------------- MoE bookkeeping (16-expert merged) ----------------
__global__ void k_moe_init(int* cnt, int* cnt2, int* joblist) {
  int i = blockIdx.x * 256 + threadIdx.x;
  if (i < JOBCAP) joblist[i] = -1;
  if (i < 16) { cnt[i] = 0; cnt2[i] = 0; }
}
__global__ void k_moe_count(const int* __restrict__ topidx, int* __restrict__ cnt) {
  int t = blockIdx.x * 256 + threadIdx.x;     // global token 0..2*TOK
  if (t >= 2 * TOK) return;
  int lo = (t >= TOK) ? 8 : 0;
  atomicAdd(&cnt[topidx[t * 2] + lo], 1);
  atomicAdd(&cnt[topidx[t * 2 + 1] + lo], 1);
}
__global__ void k_moe_offsets(const int* __restrict__ cnt, int* __restrict__ seg) {
  if (threadIdx.x == 0) {
    int o = 0;
    for (int e = 0; e < 16; e++) { seg[e] = o; o += (cnt[e] + 127) & ~127; }
    seg[16] = o;
  }
}
__global__ void k_moe_scatter(const int* __restrict__ topidx, int* __restrict__ cnt2,
                              const int* __restrict__ seg, int* __restrict__ joblist,
                              int* __restrict__ tokpos) {
  int t = blockIdx.x * 256 + threadIdx.x;
  if (t >= 2 * TOK) return;
  int lo = (t >= TOK) ? 8 : 0;
  #pragma unroll
  for (int s = 0; s < 2; s++) {
    int e = topidx[t * 2 + s] + lo;
    int p = atomicAdd(&cnt2[e], 1);
    int pos = seg[e] + p;
    joblist[pos] = t;                 // global row into xlnb[2*TOK]
    tokpos[t * 2 + s] = pos;
  }
}
__global__ void k_combine(const float* __restrict__ y, const float* __restrict__ gates,
                          const int* __restrict__ tokpos, float* __restrict__ out) {
  int t = blockIdx.x, tid = threadIdx.x;
  int p0 = tokpos[t * 2], p1 = tokpos[t * 2 + 1];
  float g0 = gates[t * 2], g1 = gates[t * 2 + 1];
  float4 a = ((const float4*)(y + (size_t)p0 * DM))[tid];
  float4 b = ((const float4*)(y + (size_t)p1 * DM))[tid];
  float4 o;
  o.x = g0 * a.x + g1 * b.x; o.y = g0 * a.y + g1 * b.y;
  o.z = g0 * a.z + g1 * b.z; o.w = g0 * a.w + g1 * b.w;
  ((float4*)(out + (size_t)t * DM))[tid] = o;
}

// ---------------- feature mean (two-stage) + classifier ----------------
__global__ void k_feat1(const float* __restrict__ second, float* __restrict__ part) {
  int b = blockIdx.x, c = blockIdx.y, tid = threadIdx.x;
  const float* p = second + ((size_t)b * SEQ + (size_t)c * 64) * DM;
  float4 s = {0.f, 0.f, 0.f, 0.f};
  for (int j = 0; j < 64; ++j) {
    float4 v = ((const float4*)(p + (size_t)j * DM))[tid];
    s.x += v.x; s.y += v.y; s.z += v.z; s.w += v.w;
  }
  ((float4*)(part + (size_t)(b * 8 + c) * DM))[tid] = s;
}
__global__ void k_feat2(const float* __restrict__ part, float* __restrict__ feat) {
  int i = blockIdx.x * 256 + threadIdx.x;
  int b = i >> 10, d = i & 1023;
  float s = 0.f;
  #pragma unroll
  for (int c = 0; c < 8; ++c) s += part[(size_t)(b * 8 + c) * DM + d];
  feat[i] = s * (1.f / SEQ);
}
__global__ void k_cls(const float* __restrict__ feat, const float* __restrict__ Wc,
                      const float* __restrict__ bc, float* __restrict__ cls) {
  int o = blockIdx.x; int b = o / 10, n = o % 10; int l = threadIdx.x;
  float s = 0.f;
  for (int d = l; d < DM; d += 64) s += feat[b * DM + d] * Wc[(size_t)d * 10 + n];
  for (int off = 32; off; off >>= 1) s += __shfl_down(s, off);
  if (l == 0) cls[o] = s + bc[n];
}

// ---------------- launch ----------------
extern "C" void kernel_launch(void* const* d_in, const int* in_sizes, int n_in,
                              void* d_out, int out_size, void* d_ws, size_t ws_size,
                              hipStream_t stream) {
  const int*   ids    = (const int*)d_in[0];
  const float* emb    = (const float*)d_in[2];
  const float* pos    = (const float*)d_in[3];
  const float* Wq     = (const float*)d_in[4];
  const float* Wk     = (const float*)d_in[5];
  const float* Wv     = (const float*)d_in[6];
  const float* Wo     = (const float*)d_in[7];
  const float* bo     = (const float*)d_in[8];
  const float* g1     = (const float*)d_in[9];
  const float* be1    = (const float*)d_in[10];
  const float* g2     = (const float*)d_in[11];
  const float* be2    = (const float*)d_in[12];
  const float* g3     = (const float*)d_in[13];
  const float* be3    = (const float*)d_in[14];
  const float* Wr1    = (const float*)d_in[15];
  const float* br1    = (const float*)d_in[16];
  const float* Wn1    = (const float*)d_in[17];
  const float* bn1    = (const float*)d_in[18];
  const float* W1a    = (const float*)d_in[19];
  const float* b1a    = (const float*)d_in[20];
  const float* W2a    = (const float*)d_in[21];
  const float* b2a    = (const float*)d_in[22];
  const float* Wr2    = (const float*)d_in[23];
  const float* br2    = (const float*)d_in[24];
  const float* Wn2    = (const float*)d_in[25];
  const float* bn2    = (const float*)d_in[26];
  const float* W1b    = (const float*)d_in[27];
  const float* b1b    = (const float*)d_in[28];
  const float* W2b    = (const float*)d_in[29];
  const float* b2b    = (const float*)d_in[30];
  const float* noise1 = (const float*)d_in[31];
  const float* noise2 = (const float*)d_in[32];
  const float* Wc     = (const float*)d_in[33];
  const float* bc     = (const float*)d_in[34];

  char* wsp = (char*)d_ws; size_t off = 0;
  auto alloc = [&](size_t bytes) -> void* {
    void* p = wsp + off; off += (bytes + 255) & ~(size_t)255; return p;
  };
  char*  G     = (char*)alloc(360710144);              // phase-overlaid big region (344MB)
  float* x     = (float*)alloc((size_t)TOK * DM * 4);
  float* x2    = (float*)alloc((size_t)TOK * DM * 4);
  u16*   xlnb  = (u16*)alloc((size_t)2 * TOK * DM * 2);   // both layers' LN
  float* gates  = (float*)alloc(2 * TOK * 2 * 4);
  int*   topidx = (int*)alloc(2 * TOK * 2 * 4);
  int*   cnt    = (int*)alloc(16 * 4);
  int*   cnt2   = (int*)alloc(16 * 4);
  int*   seg    = (int*)alloc(24 * 4);
  int*   joblist= (int*)alloc(JOBCAP * 4);
  int*   tokpos = (int*)alloc(2 * TOK * 2 * 4);
  float* fpart  = (float*)alloc(64 * DM * 4);
  (void)ws_size; (void)in_sizes; (void)n_in; (void)out_size;

  // attention-phase views (~164MB of G)
  u16* WQKVTh = (u16*)(G + 0);
  u16* WQKVTl = (u16*)(G + 6291456);
  u16* WOTh   = (u16*)(G + 12582912);
  u16* WOTl   = (u16*)(G + 14680064);
  u16* XLNH   = (u16*)(G + 16777216);
  u16* XLNL   = (u16*)(G + 25165824);
  u16* QH     = (u16*)(G + 33554432);
  u16* QL     = (u16*)(G + 41943040);
  u16* KH     = (u16*)(G + 50331648);
  u16* KL     = (u16*)(G + 58720256);
  u16* VTh    = (u16*)(G + 67108864);
  u16* VTl    = (u16*)(G + 75497472);
  u16* OH     = (u16*)(G + 83886080);
  u16* OL     = (u16*)(G + 92274688);
  float* SC   = (float*)(G + 100663296);  // [64][512][512] f32 -> att hi/lo in place
  // moe-phase views (344MB of G; attention buffers dead by then)
  u16*   H    = (u16*)(G + 0);            // [18432][4096] bf16 (151MB)
  float* Y    = (float*)(G + 150994944);  // [18432][1024] f32 (75.5MB)
  u16*   WBUF = (u16*)(G + 226492416);    // 16 experts' weights bf16 (128MB)

  float* out_first  = (float*)d_out;
  float* out_second = out_first + (size_t)TOK * DM;
  float* feat       = out_first + (size_t)2 * TOK * DM;
  float* cls        = feat + 8 * DM;

  dim3 tb(32, 8);
  // ---- attention phase: split-bf16 3-pass ----
  hipLaunchKernelGGL(k_tcvt_split4, dim3(32, 32, 4), tb, 0, stream, Wq, Wk, Wv, Wo,
                     WQKVTh, WQKVTl, WOTh, WOTl);
  hipLaunchKernelGGL(k_embed, dim3(TOK), dim3(256), 0, stream, ids, emb, x);
  hipLaunchKernelGGL(k_ln2, dim3(TOK), dim3(256), 0, stream, x, g1, be1, XLNH, XLNL);

  GemmHArgs qa{};
  qa.Ah = XLNH; qa.Al = XLNL; qa.Bh = WQKVTh; qa.Bl = WQKVTl;
  qa.D0h = QH; qa.D0l = QL; qa.D1h = KH; qa.D1l = KL; qa.D2h = VTh; qa.D2l = VTl;
  qa.lda = DM; qa.ldb = DM; qa.K = DM;
  hipLaunchKernelGGL(gemm_h<HOP_QKV>, dim3(768), dim3(256), 0, stream, qa);

  GemmHArgs sa{};
  sa.Ah = QH; sa.Al = QL; sa.Bh = KH; sa.Bl = KL; sa.Cf = SC;
  sa.lda = DM; sa.ldb = DM; sa.K = HD;
  hipLaunchKernelGGL(gemm_h<HOP_SCORES>, dim3(640), dim3(256), 0, stream, sa);
  hipLaunchKernelGGL(k_softmax_h, dim3(SEQ, 64), dim3(256), 0, stream, SC);

  GemmHArgs pa{};
  pa.Ah = (const u16*)SC; pa.Bh = VTh; pa.Bl = VTl;
  pa.D0h = OH; pa.D0l = OL;
  pa.lda = 1024; pa.ldb = 512; pa.K = SEQ;
  hipLaunchKernelGGL(gemm_h<HOP_PV>, dim3(4, 1, 64), dim3(256), 0, stream, pa);

  GemmHArgs pj{};
  pj.Ah = OH; pj.Al = OL; pj.Bh = WOTh; pj.Bl = WOTl; pj.Cf = x2;
  pj.bias = bo; pj.resid = x; pj.pos = pos;
  pj.lda = DM; pj.ldb = DM; pj.K = DM;
  hipLaunchKernelGGL(gemm_h<HOP_PROJ>, dim3(256), dim3(256), 0, stream, pj);

  // ---- MoE phase: both layers merged into one 16-expert batch ----
  hipLaunchKernelGGL(k_lnrouter, dim3(TOK), dim3(256), 0, stream, x2, g2, be2,
                     Wr1, br1, Wn1, bn1, noise1, xlnb, gates, topidx);
  hipLaunchKernelGGL(k_lnrouter, dim3(TOK), dim3(256), 0, stream, x2, g3, be3,
                     Wr2, br2, Wn2, bn2, noise2, xlnb + (size_t)TOK * DM,
                     gates + (size_t)TOK * 2, topidx + (size_t)TOK * 2);
  hipLaunchKernelGGL(k_moe_init, dim3(72), dim3(256), 0, stream, cnt, cnt2, joblist);
  hipLaunchKernelGGL(k_moe_count, dim3(32), dim3(256), 0, stream, topidx, cnt);
  hipLaunchKernelGGL(k_moe_offsets, dim3(1), dim3(64), 0, stream, cnt, seg);
  hipLaunchKernelGGL(k_moe_scatter, dim3(32), dim3(256), 0, stream, topidx, cnt2, seg, joblist, tokpos);

  hipLaunchKernelGGL(k_tcvt64, dim3(16, 64, 16), tb, 0, stream, W1a, W1b, WBUF, DM, FF);
  GemmArgs m1{};
  m1.A = xlnb; m1.B = WBUF; m1.C = H; m1.b1a = b1a; m1.b1b = b1b;
  m1.joblist = joblist; m1.seg = seg;
  m1.lda = DM; m1.ldb = DM; m1.K = DM;
  hipLaunchKernelGGL(gemm_k<OP_MOE1>, dim3(4608), dim3(256), 0, stream, m1);

  hipLaunchKernelGGL(k_tcvt64, dim3(64, 16, 16), tb, 0, stream, W2a, W2b, WBUF, FF, DM);
  GemmArgs m2{};
  m2.A = H; m2.B = WBUF; m2.C = Y; m2.b1a = b2a; m2.b1b = b2b;
  m2.joblist = joblist; m2.seg = seg;
  m2.lda = FF; m2.ldb = FF; m2.K = FF;
  hipLaunchKernelGGL(gemm_k<OP_MOE2>, dim3(1152), dim3(256), 0, stream, m2);

  hipLaunchKernelGGL(k_combine, dim3(TOK), dim3(256), 0, stream, Y, gates, tokpos, out_first);
  hipLaunchKernelGGL(k_combine, dim3(TOK), dim3(256), 0, stream, Y,
                     gates + (size_t)TOK * 2, tokpos + (size_t)TOK * 2, out_second);

  hipLaunchKernelGGL(k_feat1, dim3(8, 8), dim3(256), 0, stream, out_second, fpart);
  hipLaunchKernelGGL(k_feat2, dim3(32), dim3(256), 0, stream, fpart, feat);
  hipLaunchKernelGGL(k_cls, dim3(80), dim3(64), 0, stream, feat, Wc, bc, cls);
}

// Round 14
// 1177.183 us; speedup vs baseline: 1.0330x; 1.0330x over previous
//
#include <hip/hip_runtime.h>
#include <cstdint>

typedef unsigned short u16;
typedef __attribute__((ext_vector_type(8))) __bf16 bf16x8;
typedef __attribute__((ext_vector_type(4))) float f32x4;

#define TOK 4096
#define DM  1024
#define EXP 8
#define FF  4096
#define SEQ 512
#define NH  8
#define HD  128
#define JOBCAP 18432

__device__ __forceinline__ u16 f2bf(float f) {
  union { float f; unsigned int u; } v; v.f = f;
  unsigned int u = v.u;
  u += 0x7FFFu + ((u >> 16) & 1u);   // round-to-nearest-even
  return (u16)(u >> 16);
}
__device__ __forceinline__ float bf2f(u16 h) {
  union { unsigned int u; float f; } v; v.u = ((unsigned int)h) << 16; return v.f;
}

// async global->LDS, 16B per lane; dest = wave-uniform base + lane*16
__device__ __forceinline__ void gl_lds16(const u16* g, u16* l) {
  __builtin_amdgcn_global_load_lds(
      (const __attribute__((address_space(1))) unsigned int*)g,
      (__attribute__((address_space(3))) unsigned int*)l, 16, 0, 0);
}

// ---------------- embed gather ----------------
__global__ void k_embed(const int* __restrict__ ids, const float* __restrict__ emb,
                        float* __restrict__ x) {
  int t = blockIdx.x;
  int id = ids[t];
  const float4* src = (const float4*)(emb + (size_t)id * DM);
  float4* dst = (float4*)(x + (size_t)t * DM);
  dst[threadIdx.x] = src[threadIdx.x];
}

// ---------------- fused layernorm(bf16 out) + router (MoE path) ----------------
__global__ void k_lnrouter(const float* __restrict__ xin, const float* __restrict__ g,
                           const float* __restrict__ be,
                           const float* __restrict__ Wr, const float* __restrict__ br,
                           const float* __restrict__ Wn, const float* __restrict__ bn,
                           const float* __restrict__ noise,
                           u16* __restrict__ obf,
                           float* __restrict__ gates, int* __restrict__ topidx) {
  int t = blockIdx.x, tid = threadIdx.x;
  float4 v = ((const float4*)(xin + (size_t)t * DM))[tid];
  float s = v.x + v.y + v.z + v.w;
  float sq = v.x*v.x + v.y*v.y + v.z*v.z + v.w*v.w;
  for (int o = 32; o; o >>= 1) { s += __shfl_down(s, o); sq += __shfl_down(sq, o); }
  __shared__ float ss[4], sqs[4];
  if ((tid & 63) == 0) { ss[tid >> 6] = s; sqs[tid >> 6] = sq; }
  __syncthreads();
  s  = ss[0] + ss[1] + ss[2] + ss[3];
  sq = sqs[0] + sqs[1] + sqs[2] + sqs[3];
  float mean = s * (1.f / DM);
  float var  = sq * (1.f / DM) - mean * mean;
  float rstd = rsqrtf(var + 1e-5f);
  float4 gg = ((const float4*)g)[tid];
  float4 bb = ((const float4*)be)[tid];
  float xl[4];
  xl[0] = (v.x - mean) * rstd * gg.x + bb.x;
  xl[1] = (v.y - mean) * rstd * gg.y + bb.y;
  xl[2] = (v.z - mean) * rstd * gg.z + bb.z;
  xl[3] = (v.w - mean) * rstd * gg.w + bb.w;
  ushort4 u;
  u.x = f2bf(xl[0]); u.y = f2bf(xl[1]); u.z = f2bf(xl[2]); u.w = f2bf(xl[3]);
  ((ushort4*)(obf + (size_t)t * DM))[tid] = u;

  float pl[8], pn[8];
  #pragma unroll
  for (int e = 0; e < 8; e++) { pl[e] = 0.f; pn[e] = 0.f; }
  #pragma unroll
  for (int j = 0; j < 4; j++) {
    int d = tid * 4 + j;
    float xv = xl[j];
    const float4* wr = (const float4*)(Wr + (size_t)d * 8);
    const float4* wn = (const float4*)(Wn + (size_t)d * 8);
    float4 a0 = wr[0], a1 = wr[1], c0 = wn[0], c1 = wn[1];
    pl[0] += xv * a0.x; pl[1] += xv * a0.y; pl[2] += xv * a0.z; pl[3] += xv * a0.w;
    pl[4] += xv * a1.x; pl[5] += xv * a1.y; pl[6] += xv * a1.z; pl[7] += xv * a1.w;
    pn[0] += xv * c0.x; pn[1] += xv * c0.y; pn[2] += xv * c0.z; pn[3] += xv * c0.w;
    pn[4] += xv * c1.x; pn[5] += xv * c1.y; pn[6] += xv * c1.z; pn[7] += xv * c1.w;
  }
  for (int o = 32; o; o >>= 1) {
    #pragma unroll
    for (int e = 0; e < 8; e++) { pl[e] += __shfl_down(pl[e], o); pn[e] += __shfl_down(pn[e], o); }
  }
  __shared__ float sl[4][8], sn[4][8];
  if ((tid & 63) == 0) {
    int w = tid >> 6;
    #pragma unroll
    for (int e = 0; e < 8; e++) { sl[w][e] = pl[e]; sn[w][e] = pn[e]; }
  }
  __syncthreads();
  if (tid == 0) {
    float noisy[8];
    #pragma unroll
    for (int e = 0; e < 8; e++) {
      float l  = sl[0][e] + sl[1][e] + sl[2][e] + sl[3][e] + br[e];
      float nn = sn[0][e] + sn[1][e] + sn[2][e] + sn[3][e] + bn[e];
      float sp = (nn > 20.f) ? nn : log1pf(expf(nn));
      noisy[e] = l + noise[(size_t)t * 8 + e] * sp;
    }
    int i0 = 0;
    for (int e = 1; e < 8; e++) if (noisy[e] > noisy[i0]) i0 = e;
    int i1 = (i0 == 0) ? 1 : 0;
    for (int e = 0; e < 8; e++) if (e != i0 && noisy[e] > noisy[i1]) i1 = e;
    float e1 = expf(noisy[i1] - noisy[i0]);
    float zz = 1.f + e1;
    gates[t * 2] = 1.f / zz; gates[t * 2 + 1] = e1 / zz;
    topidx[t * 2] = i0; topidx[t * 2 + 1] = i1;
  }
}

// ---------------- layernorm -> hi/lo bf16 pair (attention path) ----------------
__global__ void k_ln2(const float* __restrict__ in, const float* __restrict__ g,
                      const float* __restrict__ be, u16* __restrict__ oh,
                      u16* __restrict__ ol) {
  int t = blockIdx.x, tid = threadIdx.x;
  float4 v = ((const float4*)(in + (size_t)t * DM))[tid];
  float s = v.x + v.y + v.z + v.w;
  float sq = v.x*v.x + v.y*v.y + v.z*v.z + v.w*v.w;
  for (int o = 32; o; o >>= 1) { s += __shfl_down(s, o); sq += __shfl_down(sq, o); }
  __shared__ float ss[4], sqs[4];
  if ((tid & 63) == 0) { ss[tid >> 6] = s; sqs[tid >> 6] = sq; }
  __syncthreads();
  s  = ss[0] + ss[1] + ss[2] + ss[3];
  sq = sqs[0] + sqs[1] + sqs[2] + sqs[3];
  float mean = s * (1.f / DM);
  float var  = sq * (1.f / DM) - mean * mean;
  float rstd = rsqrtf(var + 1e-5f);
  float4 gg = ((const float4*)g)[tid];
  float4 bb = ((const float4*)be)[tid];
  float o4[4];
  o4[0] = (v.x - mean) * rstd * gg.x + bb.x;
  o4[1] = (v.y - mean) * rstd * gg.y + bb.y;
  o4[2] = (v.z - mean) * rstd * gg.z + bb.z;
  o4[3] = (v.w - mean) * rstd * gg.w + bb.w;
  ushort4 uh, ul;
  u16* ph = (u16*)&uh; u16* pl = (u16*)&ul;
  #pragma unroll
  for (int i = 0; i < 4; i++) {
    u16 hi = f2bf(o4[i]); ph[i] = hi; pl[i] = f2bf(o4[i] - bf2f(hi));
  }
  ((ushort4*)(oh + (size_t)t * DM))[tid] = uh;
  ((ushort4*)(ol + (size_t)t * DM))[tid] = ul;
}

// ---------------- transpose f32 [1024,1024] -> hi/lo bf16, 4 weights batched ----------------
__global__ void k_tcvt_split4(const float* __restrict__ Wq, const float* __restrict__ Wk,
                              const float* __restrict__ Wv, const float* __restrict__ Wo,
                              u16* __restrict__ qkvh, u16* __restrict__ qkvl,
                              u16* __restrict__ oh, u16* __restrict__ ol) {
  __shared__ float t[32][33];
  int z = blockIdx.z;
  const float* src = (z == 0) ? Wq : (z == 1) ? Wk : (z == 2) ? Wv : Wo;
  u16* dh = (z < 3) ? qkvh + (size_t)z * DM * DM : oh;
  u16* dl = (z < 3) ? qkvl + (size_t)z * DM * DM : ol;
  int k0 = blockIdx.x * 32, n0 = blockIdx.y * 32;
  int tx = threadIdx.x, ty = threadIdx.y;
  #pragma unroll
  for (int i = 0; i < 4; i++) t[ty + 8*i][tx] = src[(size_t)(k0 + ty + 8*i) * DM + n0 + tx];
  __syncthreads();
  int u = ty * 32 + tx;
  int r = u >> 3, kq = u & 7;
  ushort4 ohv, olv;
  u16* ph = (u16*)&ohv; u16* pl = (u16*)&olv;
  #pragma unroll
  for (int i = 0; i < 4; i++) {
    float v = t[kq*4+i][r];
    u16 hi = f2bf(v); ph[i] = hi; pl[i] = f2bf(v - bf2f(hi));
  }
  *(ushort4*)&dh[(size_t)(n0 + r) * DM + k0 + kq*4] = ohv;
  *(ushort4*)&dl[(size_t)(n0 + r) * DM + k0 + kq*4] = olv;
}

// ---------------- transpose f32 [K,N] -> bf16 [N,K], 64x64 tiles, 16-expert dual-source ----------------
__global__ void k_tcvt64(const float* __restrict__ srcA, const float* __restrict__ srcB,
                         u16* __restrict__ dst, int K, int N) {
  __shared__ float t[64][65];
  int z = blockIdx.z;
  const float* src = (z < 8) ? srcA + (size_t)z * K * N : srcB + (size_t)(z - 8) * K * N;
  u16* d = dst + (size_t)z * K * N;
  int k0 = blockIdx.x * 64, n0 = blockIdx.y * 64;
  int u = threadIdx.y * 32 + threadIdx.x;
  #pragma unroll
  for (int i = 0; i < 4; i++) {
    int idx = u + i * 256;
    int kr = idx >> 4, nq = (idx & 15) * 4;
    float4 v = *(const float4*)&src[(size_t)(k0 + kr) * N + n0 + nq];
    t[kr][nq] = v.x; t[kr][nq+1] = v.y; t[kr][nq+2] = v.z; t[kr][nq+3] = v.w;
  }
  __syncthreads();
  #pragma unroll
  for (int j = 0; j < 2; j++) {
    int idx = u + j * 256;
    int nr = idx >> 3, kq = (idx & 7) * 8;
    ushort4 o0, o1;
    u16* p0 = (u16*)&o0; u16* p1 = (u16*)&o1;
    #pragma unroll
    for (int i = 0; i < 4; i++) p0[i] = f2bf(t[kq + i][nr]);
    #pragma unroll
    for (int i = 0; i < 4; i++) p1[i] = f2bf(t[kq + 4 + i][nr]);
    *(ushort4*)&d[(size_t)(n0 + nr) * K + k0 + kq]     = o0;
    *(ushort4*)&d[(size_t)(n0 + nr) * K + k0 + kq + 4] = o1;
  }
}

// ---------------- causal softmax f32 -> att hi/lo bf16 in place ----------------
__global__ void k_softmax_h(float* __restrict__ scores) {
  int q = blockIdx.x, bh = blockIdx.y, tid = threadIdx.x;
  float* row = scores + ((size_t)bh * 512 + q) * 512;
  u16* orow = (u16*)row;
  const float scale = 0.088388347648318447f; // 128^-0.5
  int j0 = tid * 2;
  float v0 = -1e30f, v1 = -1e30f;
  if (j0 <= q)     v0 = row[j0] * scale;
  if (j0 + 1 <= q) v1 = row[j0 + 1] * scale;
  float m = fmaxf(v0, v1);
  for (int o = 32; o; o >>= 1) m = fmaxf(m, __shfl_down(m, o));
  __shared__ float sm[4], ssum[4];
  if ((tid & 63) == 0) sm[tid >> 6] = m;
  __syncthreads();
  m = fmaxf(fmaxf(sm[0], sm[1]), fmaxf(sm[2], sm[3]));
  float p0 = (j0 <= q)     ? expf(v0 - m) : 0.f;
  float p1 = (j0 + 1 <= q) ? expf(v1 - m) : 0.f;
  float s = p0 + p1;
  for (int o = 32; o; o >>= 1) s += __shfl_down(s, o);
  if ((tid & 63) == 0) ssum[tid >> 6] = s;
  __syncthreads();
  s = ssum[0] + ssum[1] + ssum[2] + ssum[3];
  float inv = 1.f / s;
  float pi0 = p0 * inv, pi1 = p1 * inv;
  u16 h0 = f2bf(pi0), h1 = f2bf(pi1);
  orow[j0]       = h0; orow[j0 + 1]       = h1;
  orow[512 + j0] = f2bf(pi0 - bf2f(h0));
  orow[512 + j0 + 1] = f2bf(pi1 - bf2f(h1));
}

// ---------------- split-bf16 3-pass MFMA GEMM (attention path) ----------------
constexpr int HOP_QKV    = 0;
constexpr int HOP_SCORES = 1;
constexpr int HOP_PV     = 2;
constexpr int HOP_PROJ   = 3;

struct GemmHArgs {
  const u16 *Ah, *Al, *Bh, *Bl;
  u16 *D0h, *D0l, *D1h, *D1l, *D2h, *D2l;
  float *Cf;
  const float *bias, *resid, *pos;
  int lda, ldb, K;
};

template<int OP>
__launch_bounds__(256, 4)
__global__ void gemm_h(GemmHArgs p) {
  int bx, by, z;
  if constexpr (OP == HOP_QKV) {
    int bid = blockIdx.x; int xcd = bid & 7, slot = bid >> 3;
    by = xcd * 3 + (slot >> 5); bx = slot & 31; z = 0;
  } else if constexpr (OP == HOP_PROJ) {
    int bid = blockIdx.x; by = bid & 7; bx = bid >> 3; z = 0;
  } else if constexpr (OP == HOP_SCORES) { // dense triangular: 10 tiles x 64 bh
    int bid = blockIdx.x; z = bid / 10; int t = bid % 10;
    bx = (t >= 6) ? 3 : (t >= 3) ? 2 : (t >= 1) ? 1 : 0;
    by = t - ((bx * (bx + 1)) >> 1);
  } else {
    bx = blockIdx.x; by = blockIdx.y; z = blockIdx.z;
  }

  const u16 *Ahb, *Alb, *Bhb, *Blb;
  if constexpr (OP == HOP_SCORES) {
    size_t off = (size_t)(z >> 3) * 524288 + (size_t)(z & 7) * 128;
    Ahb = p.Ah + off; Alb = p.Al + off; Bhb = p.Bh + off; Blb = p.Bl + off;
  } else if constexpr (OP == HOP_PV) {
    size_t aoff = (size_t)z * 524288;
    Ahb = p.Ah + aoff; Alb = p.Ah + aoff + 512;
    size_t boff = (size_t)z * 65536;
    Bhb = p.Bh + boff; Blb = p.Bl + boff;
  } else {
    Ahb = p.Ah; Alb = p.Al; Bhb = p.Bh; Blb = p.Bl;
  }

  int kmax = p.K;
  if constexpr (OP == HOP_PV) { int lim = bx * 128 + 128; kmax = lim < p.K ? lim : p.K; }
  int nt = kmax >> 5;

  __shared__ __align__(16) u16 As[2 * 4096];
  __shared__ __align__(16) u16 Bs[2 * 4096];

  int tid = threadIdx.x, lane = tid & 63, wid = tid >> 6;
  int srow = wid * 16 + (lane >> 2), skoff = (lane & 3) * 8;
  int lo0 = (wid * 16) * 32, lo1 = ((wid + 4) * 16) * 32;
  int wr = wid >> 1, wc = wid & 1, fm = lane & 15, fk = (lane >> 4) * 8;

  f32x4 acc[4][4] = {};
  const size_t lda = p.lda, ldb = p.ldb;

  #pragma unroll 1
  for (int pass = 0; pass < 3; ++pass) {
    const u16* Ab = (pass < 2) ? Ahb : Alb;
    const u16* Bb = (pass & 1) ? Blb : Bhb;
    const u16* aptr0 = Ab + (size_t)(bx * 128 + srow) * lda + skoff;
    const u16* aptr1 = Ab + (size_t)(bx * 128 + 64 + srow) * lda + skoff;
    const u16* bptr0 = Bb + (size_t)(by * 128 + srow) * ldb + skoff;
    const u16* bptr1 = Bb + (size_t)(by * 128 + 64 + srow) * ldb + skoff;

    gl_lds16(aptr0, &As[lo0]); gl_lds16(aptr1, &As[lo1]);
    gl_lds16(bptr0, &Bs[lo0]); gl_lds16(bptr1, &Bs[lo1]);
    __syncthreads();
    int cur = 0;
    for (int t = 0; t < nt; ++t) {
      if (t + 1 < nt) {
        int nxt = (cur ^ 1) * 4096;
        int k0 = (t + 1) * 32;
        gl_lds16(aptr0 + k0, &As[nxt + lo0]); gl_lds16(aptr1 + k0, &As[nxt + lo1]);
        gl_lds16(bptr0 + k0, &Bs[nxt + lo0]); gl_lds16(bptr1 + k0, &Bs[nxt + lo1]);
      }
      int cb = cur * 4096;
      bf16x8 af[4], bfr[4];
      #pragma unroll
      for (int i = 0; i < 4; ++i) {
        af[i]  = *(const bf16x8*)&As[cb + (wr * 64 + i * 16 + fm) * 32 + fk];
        bfr[i] = *(const bf16x8*)&Bs[cb + (wc * 64 + i * 16 + fm) * 32 + fk];
      }
      #pragma unroll
      for (int mi = 0; mi < 4; ++mi)
        #pragma unroll
        for (int ni = 0; ni < 4; ++ni)
          acc[mi][ni] = __builtin_amdgcn_mfma_f32_16x16x32_bf16(af[mi], bfr[ni], acc[mi][ni], 0, 0, 0);
      __syncthreads();
      cur ^= 1;
    }
  }

  int rb = (lane >> 4) * 4, cl = lane & 15;
  #pragma unroll
  for (int mi = 0; mi < 4; ++mi)
    #pragma unroll
    for (int ni = 0; ni < 4; ++ni)
      #pragma unroll
      for (int j = 0; j < 4; ++j) {
        int m = bx * 128 + wr * 64 + mi * 16 + rb + j;
        int n = by * 128 + wc * 64 + ni * 16 + cl;
        float v = acc[mi][ni][j];
        if constexpr (OP == HOP_QKV) {
          u16 hi = f2bf(v); u16 lo = f2bf(v - bf2f(hi));
          int sel = n >> 10, nn = n & 1023;
          if (sel == 0) {
            p.D0h[(size_t)m * DM + nn] = hi; p.D0l[(size_t)m * DM + nn] = lo;
          } else if (sel == 1) {
            p.D1h[(size_t)m * DM + nn] = hi; p.D1l[(size_t)m * DM + nn] = lo;
          } else {
            size_t idx = (size_t)((m >> 9) * 8 + (nn >> 7)) * 65536 + (size_t)(nn & 127) * 512 + (m & 511);
            p.D2h[idx] = hi; p.D2l[idx] = lo;
          }
        } else if constexpr (OP == HOP_SCORES) {
          p.Cf[(size_t)z * 262144 + (size_t)m * 512 + n] = v;
        } else if constexpr (OP == HOP_PV) {
          u16 hi = f2bf(v); u16 lo = f2bf(v - bf2f(hi));
          size_t idx = (size_t)(z >> 3) * 524288 + (size_t)m * 1024 + (size_t)(z & 7) * 128 + n;
          p.D0h[idx] = hi; p.D0l[idx] = lo;
        } else { // HOP_PROJ
          size_t idx = (size_t)m * 1024 + n;
          p.Cf[idx] = v + p.bias[n] + p.resid[idx] + p.pos[(size_t)(m & 511) * 1024 + n];
        }
      }
}

// ---------------- bf16 MFMA 128x128 TN GEMM, 2-phase dbuf, 16-expert merged (MoE) ----------------
constexpr int OP_MOE1 = 0; // gathered A rows (joblist -> xlnb[2*TOK]), bf16 C=relu(acc+b1)
constexpr int OP_MOE2 = 1; // contiguous padded A rows, f32 C=acc+b2

struct GemmArgs {
  const u16* A; const u16* B; void* C;
  const float* b1a; const float* b1b;   // per-half bias arrays (8 experts each)
  const int* joblist; const int* seg;   // seg[0..16]
  int lda, ldb, K;
};

template<int OP>
__launch_bounds__(256, 4)
__global__ void gemm_k(GemmArgs p) {
  int bid = blockIdx.x;
  int xcd = bid & 7, slot = bid >> 3;
  int bx, by;
  if constexpr (OP == OP_MOE1) {
    by = xcd * 4 + (slot & 3);        // grid 4608
    bx = slot >> 2;
  } else {
    bx = xcd * 18 + (slot >> 3);      // grid 1152
    by = slot & 7;
  }
  int r0g = bx * 128;
  if (r0g >= p.seg[16]) return;
  int z = 0;
  #pragma unroll
  for (int e = 1; e < 16; ++e) z += (r0g >= p.seg[e]) ? 1 : 0;
  const u16* Bbase = p.B + (size_t)z * 4194304;
  const float* bias = (z < 8) ? p.b1a + (size_t)z * (OP == OP_MOE1 ? FF : DM)
                              : p.b1b + (size_t)(z - 8) * (OP == OP_MOE1 ? FF : DM);

  __shared__ __align__(16) u16 As[2 * 4096];
  __shared__ __align__(16) u16 Bs[2 * 4096];

  int tid = threadIdx.x;
  int lane = tid & 63, wid = tid >> 6;

  int srow = wid * 16 + (lane >> 2);
  int skoff = (lane & 3) * 8;

  const u16 *aptr0, *aptr1;
  if constexpr (OP == OP_MOE1) {
    int j0 = p.joblist[r0g + srow];
    int j1 = p.joblist[r0g + 64 + srow];
    aptr0 = p.A + (size_t)(j0 < 0 ? 0 : j0) * p.lda + skoff;
    aptr1 = p.A + (size_t)(j1 < 0 ? 0 : j1) * p.lda + skoff;
  } else {
    aptr0 = p.A + (size_t)(r0g + srow) * p.lda + skoff;
    aptr1 = p.A + (size_t)(r0g + 64 + srow) * p.lda + skoff;
  }
  const u16* bptr0 = Bbase + (size_t)(by * 128 + srow) * p.ldb + skoff;
  const u16* bptr1 = Bbase + (size_t)(by * 128 + 64 + srow) * p.ldb + skoff;

  int lo0 = (wid * 16) * 32;
  int lo1 = ((wid + 4) * 16) * 32;

  int wr = wid >> 1, wc = wid & 1;
  int fm = lane & 15;
  int fk = (lane >> 4) * 8;

  f32x4 acc[4][4] = {};
  int nt = p.K >> 5;

  gl_lds16(aptr0, &As[lo0]); gl_lds16(aptr1, &As[lo1]);
  gl_lds16(bptr0, &Bs[lo0]); gl_lds16(bptr1, &Bs[lo1]);
  __syncthreads();

  int cur = 0;
  for (int t = 0; t < nt; ++t) {
    if (t + 1 < nt) {
      int nxt = (cur ^ 1) * 4096;
      int k0 = (t + 1) * 32;
      gl_lds16(aptr0 + k0, &As[nxt + lo0]); gl_lds16(aptr1 + k0, &As[nxt + lo1]);
      gl_lds16(bptr0 + k0, &Bs[nxt + lo0]); gl_lds16(bptr1 + k0, &Bs[nxt + lo1]);
    }
    int cb = cur * 4096;
    bf16x8 af[4], bfr[4];
    #pragma unroll
    for (int i = 0; i < 4; ++i) {
      af[i]  = *(const bf16x8*)&As[cb + (wr * 64 + i * 16 + fm) * 32 + fk];
      bfr[i] = *(const bf16x8*)&Bs[cb + (wc * 64 + i * 16 + fm) * 32 + fk];
    }
    #pragma unroll
    for (int mi = 0; mi < 4; ++mi)
      #pragma unroll
      for (int ni = 0; ni < 4; ++ni)
        acc[mi][ni] = __builtin_amdgcn_mfma_f32_16x16x32_bf16(af[mi], bfr[ni], acc[mi][ni], 0, 0, 0);
    __syncthreads();
    cur ^= 1;
  }

  int rb = (lane >> 4) * 4;
  int cl = lane & 15;
  #pragma unroll
  for (int mi = 0; mi < 4; ++mi)
    #pragma unroll
    for (int ni = 0; ni < 4; ++ni)
      #pragma unroll
      for (int j = 0; j < 4; ++j) {
        int m = r0g + wr * 64 + mi * 16 + rb + j;
        int n = by * 128 + wc * 64 + ni * 16 + cl;
        float v = acc[mi][ni][j];
        if constexpr (OP == OP_MOE1) {
          float t2 = v + bias[n];
          t2 = t2 > 0.f ? t2 : 0.f;
          ((u16*)p.C)[(size_t)m * FF + n] = f2bf(t2);
        } else {
          ((float*)p.C)[(size_t)m * DM + n] = v + bias[n];
        }
      }
}

// ---------------- MoE bookkeeping (16-expert merged) ----------------
__global__ void k_moe_init(int* cnt, int* cnt2, int* joblist) {
  int i = blockIdx.x * 256 + threadIdx.x;
  if (i < JOBCAP) joblist[i] = -1;
  if (i < 16) { cnt[i] = 0; cnt2[i] = 0; }
}
__global__ void k_moe_count(const int* __restrict__ topidx, int* __restrict__ cnt) {
  int t = blockIdx.x * 256 + threadIdx.x;     // global token 0..2*TOK
  if (t >= 2 * TOK) return;
  int lo = (t >= TOK) ? 8 : 0;
  atomicAdd(&cnt[topidx[t * 2] + lo], 1);
  atomicAdd(&cnt[topidx[t * 2 + 1] + lo], 1);
}
__global__ void k_moe_offsets(const int* __restrict__ cnt, int* __restrict__ seg) {
  if (threadIdx.x == 0) {
    int o = 0;
    for (int e = 0; e < 16; e++) { seg[e] = o; o += (cnt[e] + 127) & ~127; }
    seg[16] = o;
  }
}
__global__ void k_moe_scatter(const int* __restrict__ topidx, int* __restrict__ cnt2,
                              const int* __restrict__ seg, int* __restrict__ joblist,
                              int* __restrict__ tokpos) {
  int t = blockIdx.x * 256 + threadIdx.x;
  if (t >= 2 * TOK) return;
  int lo = (t >= TOK) ? 8 : 0;
  #pragma unroll
  for (int s = 0; s < 2; s++) {
    int e = topidx[t * 2 + s] + lo;
    int p = atomicAdd(&cnt2[e], 1);
    int pos = seg[e] + p;
    joblist[pos] = t;                 // global row into xlnb[2*TOK]
    tokpos[t * 2 + s] = pos;
  }
}
__global__ void k_combine(const float* __restrict__ y, const float* __restrict__ gates,
                          const int* __restrict__ tokpos, float* __restrict__ out) {
  int t = blockIdx.x, tid = threadIdx.x;
  int p0 = tokpos[t * 2], p1 = tokpos[t * 2 + 1];
  float g0 = gates[t * 2], g1 = gates[t * 2 + 1];
  float4 a = ((const float4*)(y + (size_t)p0 * DM))[tid];
  float4 b = ((const float4*)(y + (size_t)p1 * DM))[tid];
  float4 o;
  o.x = g0 * a.x + g1 * b.x; o.y = g0 * a.y + g1 * b.y;
  o.z = g0 * a.z + g1 * b.z; o.w = g0 * a.w + g1 * b.w;
  ((float4*)(out + (size_t)t * DM))[tid] = o;
}

// ---------------- feature mean (two-stage) + classifier ----------------
__global__ void k_feat1(const float* __restrict__ second, float* __restrict__ part) {
  int b = blockIdx.x, c = blockIdx.y, tid = threadIdx.x;
  const float* p = second + ((size_t)b * SEQ + (size_t)c * 64) * DM;
  float4 s = {0.f, 0.f, 0.f, 0.f};
  for (int j = 0; j < 64; ++j) {
    float4 v = ((const float4*)(p + (size_t)j * DM))[tid];
    s.x += v.x; s.y += v.y; s.z += v.z; s.w += v.w;
  }
  ((float4*)(part + (size_t)(b * 8 + c) * DM))[tid] = s;
}
__global__ void k_feat2(const float* __restrict__ part, float* __restrict__ feat) {
  int i = blockIdx.x * 256 + threadIdx.x;
  int b = i >> 10, d = i & 1023;
  float s = 0.f;
  #pragma unroll
  for (int c = 0; c < 8; ++c) s += part[(size_t)(b * 8 + c) * DM + d];
  feat[i] = s * (1.f / SEQ);
}
__global__ void k_cls(const float* __restrict__ feat, const float* __restrict__ Wc,
                      const float* __restrict__ bc, float* __restrict__ cls) {
  int o = blockIdx.x; int b = o / 10, n = o % 10; int l = threadIdx.x;
  float s = 0.f;
  for (int d = l; d < DM; d += 64) s += feat[b * DM + d] * Wc[(size_t)d * 10 + n];
  for (int off = 32; off; off >>= 1) s += __shfl_down(s, off);
  if (l == 0) cls[o] = s + bc[n];
}

// ---------------- launch ----------------
extern "C" void kernel_launch(void* const* d_in, const int* in_sizes, int n_in,
                              void* d_out, int out_size, void* d_ws, size_t ws_size,
                              hipStream_t stream) {
  const int*   ids    = (const int*)d_in[0];
  const float* emb    = (const float*)d_in[2];
  const float* pos    = (const float*)d_in[3];
  const float* Wq     = (const float*)d_in[4];
  const float* Wk     = (const float*)d_in[5];
  const float* Wv     = (const float*)d_in[6];
  const float* Wo     = (const float*)d_in[7];
  const float* bo     = (const float*)d_in[8];
  const float* g1     = (const float*)d_in[9];
  const float* be1    = (const float*)d_in[10];
  const float* g2     = (const float*)d_in[11];
  const float* be2    = (const float*)d_in[12];
  const float* g3     = (const float*)d_in[13];
  const float* be3    = (const float*)d_in[14];
  const float* Wr1    = (const float*)d_in[15];
  const float* br1    = (const float*)d_in[16];
  const float* Wn1    = (const float*)d_in[17];
  const float* bn1    = (const float*)d_in[18];
  const float* W1a    = (const float*)d_in[19];
  const float* b1a    = (const float*)d_in[20];
  const float* W2a    = (const float*)d_in[21];
  const float* b2a    = (const float*)d_in[22];
  const float* Wr2    = (const float*)d_in[23];
  const float* br2    = (const float*)d_in[24];
  const float* Wn2    = (const float*)d_in[25];
  const float* bn2    = (const float*)d_in[26];
  const float* W1b    = (const float*)d_in[27];
  const float* b1b    = (const float*)d_in[28];
  const float* W2b    = (const float*)d_in[29];
  const float* b2b    = (const float*)d_in[30];
  const float* noise1 = (const float*)d_in[31];
  const float* noise2 = (const float*)d_in[32];
  const float* Wc     = (const float*)d_in[33];
  const float* bc     = (const float*)d_in[34];

  char* wsp = (char*)d_ws; size_t off = 0;
  auto alloc = [&](size_t bytes) -> void* {
    void* p = wsp + off; off += (bytes + 255) & ~(size_t)255; return p;
  };
  char*  G     = (char*)alloc(360710144);              // phase-overlaid big region (344MB)
  float* x     = (float*)alloc((size_t)TOK * DM * 4);
  float* x2    = (float*)alloc((size_t)TOK * DM * 4);
  u16*   xlnb  = (u16*)alloc((size_t)2 * TOK * DM * 2);   // both layers' LN
  float* gates  = (float*)alloc(2 * TOK * 2 * 4);
  int*   topidx = (int*)alloc(2 * TOK * 2 * 4);
  int*   cnt    = (int*)alloc(16 * 4);
  int*   cnt2   = (int*)alloc(16 * 4);
  int*   seg    = (int*)alloc(24 * 4);
  int*   joblist= (int*)alloc(JOBCAP * 4);
  int*   tokpos = (int*)alloc(2 * TOK * 2 * 4);
  float* fpart  = (float*)alloc(64 * DM * 4);
  (void)ws_size; (void)in_sizes; (void)n_in; (void)out_size;

  // attention-phase views (~164MB of G)
  u16* WQKVTh = (u16*)(G + 0);
  u16* WQKVTl = (u16*)(G + 6291456);
  u16* WOTh   = (u16*)(G + 12582912);
  u16* WOTl   = (u16*)(G + 14680064);
  u16* XLNH   = (u16*)(G + 16777216);
  u16* XLNL   = (u16*)(G + 25165824);
  u16* QH     = (u16*)(G + 33554432);
  u16* QL     = (u16*)(G + 41943040);
  u16* KH     = (u16*)(G + 50331648);
  u16* KL     = (u16*)(G + 58720256);
  u16* VTh    = (u16*)(G + 67108864);
  u16* VTl    = (u16*)(G + 75497472);
  u16* OH     = (u16*)(G + 83886080);
  u16* OL     = (u16*)(G + 92274688);
  float* SC   = (float*)(G + 100663296);  // [64][512][512] f32 -> att hi/lo in place
  // moe-phase views (344MB of G; attention buffers dead by then)
  u16*   H    = (u16*)(G + 0);            // [18432][4096] bf16 (151MB)
  float* Y    = (float*)(G + 150994944);  // [18432][1024] f32 (75.5MB)
  u16*   WBUF = (u16*)(G + 226492416);    // 16 experts' weights bf16 (128MB)

  float* out_first  = (float*)d_out;
  float* out_second = out_first + (size_t)TOK * DM;
  float* feat       = out_first + (size_t)2 * TOK * DM;
  float* cls        = feat + 8 * DM;

  dim3 tb(32, 8);
  // ---- attention phase: split-bf16 3-pass ----
  hipLaunchKernelGGL(k_tcvt_split4, dim3(32, 32, 4), tb, 0, stream, Wq, Wk, Wv, Wo,
                     WQKVTh, WQKVTl, WOTh, WOTl);
  hipLaunchKernelGGL(k_embed, dim3(TOK), dim3(256), 0, stream, ids, emb, x);
  hipLaunchKernelGGL(k_ln2, dim3(TOK), dim3(256), 0, stream, x, g1, be1, XLNH, XLNL);

  GemmHArgs qa{};
  qa.Ah = XLNH; qa.Al = XLNL; qa.Bh = WQKVTh; qa.Bl = WQKVTl;
  qa.D0h = QH; qa.D0l = QL; qa.D1h = KH; qa.D1l = KL; qa.D2h = VTh; qa.D2l = VTl;
  qa.lda = DM; qa.ldb = DM; qa.K = DM;
  hipLaunchKernelGGL(gemm_h<HOP_QKV>, dim3(768), dim3(256), 0, stream, qa);

  GemmHArgs sa{};
  sa.Ah = QH; sa.Al = QL; sa.Bh = KH; sa.Bl = KL; sa.Cf = SC;
  sa.lda = DM; sa.ldb = DM; sa.K = HD;
  hipLaunchKernelGGL(gemm_h<HOP_SCORES>, dim3(640), dim3(256), 0, stream, sa);
  hipLaunchKernelGGL(k_softmax_h, dim3(SEQ, 64), dim3(256), 0, stream, SC);

  GemmHArgs pa{};
  pa.Ah = (const u16*)SC; pa.Bh = VTh; pa.Bl = VTl;
  pa.D0h = OH; pa.D0l = OL;
  pa.lda = 1024; pa.ldb = 512; pa.K = SEQ;
  hipLaunchKernelGGL(gemm_h<HOP_PV>, dim3(4, 1, 64), dim3(256), 0, stream, pa);

  GemmHArgs pj{};
  pj.Ah = OH; pj.Al = OL; pj.Bh = WOTh; pj.Bl = WOTl; pj.Cf = x2;
  pj.bias = bo; pj.resid = x; pj.pos = pos;
  pj.lda = DM; pj.ldb = DM; pj.K = DM;
  hipLaunchKernelGGL(gemm_h<HOP_PROJ>, dim3(256), dim3(256), 0, stream, pj);

  // ---- MoE phase: both layers merged into one 16-expert batch ----
  hipLaunchKernelGGL(k_lnrouter, dim3(TOK), dim3(256), 0, stream, x2, g2, be2,
                     Wr1, br1, Wn1, bn1, noise1, xlnb, gates, topidx);
  hipLaunchKernelGGL(k_lnrouter, dim3(TOK), dim3(256), 0, stream, x2, g3, be3,
                     Wr2, br2, Wn2, bn2, noise2, xlnb + (size_t)TOK * DM,
                     gates + (size_t)TOK * 2, topidx + (size_t)TOK * 2);
  hipLaunchKernelGGL(k_moe_init, dim3(72), dim3(256), 0, stream, cnt, cnt2, joblist);
  hipLaunchKernelGGL(k_moe_count, dim3(32), dim3(256), 0, stream, topidx, cnt);
  hipLaunchKernelGGL(k_moe_offsets, dim3(1), dim3(64), 0, stream, cnt, seg);
  hipLaunchKernelGGL(k_moe_scatter, dim3(32), dim3(256), 0, stream, topidx, cnt2, seg, joblist, tokpos);

  hipLaunchKernelGGL(k_tcvt64, dim3(16, 64, 16), tb, 0, stream, W1a, W1b, WBUF, DM, FF);
  GemmArgs m1{};
  m1.A = xlnb; m1.B = WBUF; m1.C = H; m1.b1a = b1a; m1.b1b = b1b;
  m1.joblist = joblist; m1.seg = seg;
  m1.lda = DM; m1.ldb = DM; m1.K = DM;
  hipLaunchKernelGGL(gemm_k<OP_MOE1>, dim3(4608), dim3(256), 0, stream, m1);

  hipLaunchKernelGGL(k_tcvt64, dim3(64, 16, 16), tb, 0, stream, W2a, W2b, WBUF, FF, DM);
  GemmArgs m2{};
  m2.A = H; m2.B = WBUF; m2.C = Y; m2.b1a = b2a; m2.b1b = b2b;
  m2.joblist = joblist; m2.seg = seg;
  m2.lda = FF; m2.ldb = FF; m2.K = FF;
  hipLaunchKernelGGL(gemm_k<OP_MOE2>, dim3(1152), dim3(256), 0, stream, m2);

  hipLaunchKernelGGL(k_combine, dim3(TOK), dim3(256), 0, stream, Y, gates, tokpos, out_first);
  hipLaunchKernelGGL(k_combine, dim3(TOK), dim3(256), 0, stream, Y,
                     gates + (size_t)TOK * 2, tokpos + (size_t)TOK * 2, out_second);

  hipLaunchKernelGGL(k_feat1, dim3(8, 8), dim3(256), 0, stream, out_second, fpart);
  hipLaunchKernelGGL(k_feat2, dim3(32), dim3(256), 0, stream, fpart, feat);
  hipLaunchKernelGGL(k_cls, dim3(80), dim3(64), 0, stream, feat, Wc, bc, cls);
}

// Round 15
// 1125.358 us; speedup vs baseline: 1.0806x; 1.0461x over previous
//
#include <hip/hip_runtime.h>
#include <cstdint>

typedef unsigned short u16;
typedef __attribute__((ext_vector_type(8))) __bf16 bf16x8;
typedef __attribute__((ext_vector_type(4))) float f32x4;

#define TOK 4096
#define DM  1024
#define EXP 8
#define FF  4096
#define SEQ 512
#define NH  8
#define HD  128
#define JOBCAP 18432

__device__ __forceinline__ u16 f2bf(float f) {
  union { float f; unsigned int u; } v; v.f = f;
  unsigned int u = v.u;
  u += 0x7FFFu + ((u >> 16) & 1u);   // round-to-nearest-even
  return (u16)(u >> 16);
}
__device__ __forceinline__ float bf2f(u16 h) {
  union { unsigned int u; float f; } v; v.u = ((unsigned int)h) << 16; return v.f;
}

// async global->LDS, 16B per lane; dest = wave-uniform base + lane*16
__device__ __forceinline__ void gl_lds16(const u16* g, u16* l) {
  __builtin_amdgcn_global_load_lds(
      (const __attribute__((address_space(1))) unsigned int*)g,
      (__attribute__((address_space(3))) unsigned int*)l, 16, 0, 0);
}

// ---------------- embed gather ----------------
__global__ void k_embed(const int* __restrict__ ids, const float* __restrict__ emb,
                        float* __restrict__ x) {
  int t = blockIdx.x;
  int id = ids[t];
  const float4* src = (const float4*)(emb + (size_t)id * DM);
  float4* dst = (float4*)(x + (size_t)t * DM);
  dst[threadIdx.x] = src[threadIdx.x];
}

// ---------------- fused layernorm(bf16 out) + router (MoE path) ----------------
__global__ void k_lnrouter(const float* __restrict__ xin, const float* __restrict__ g,
                           const float* __restrict__ be,
                           const float* __restrict__ Wr, const float* __restrict__ br,
                           const float* __restrict__ Wn, const float* __restrict__ bn,
                           const float* __restrict__ noise,
                           u16* __restrict__ obf,
                           float* __restrict__ gates, int* __restrict__ topidx) {
  int t = blockIdx.x, tid = threadIdx.x;
  float4 v = ((const float4*)(xin + (size_t)t * DM))[tid];
  float s = v.x + v.y + v.z + v.w;
  float sq = v.x*v.x + v.y*v.y + v.z*v.z + v.w*v.w;
  for (int o = 32; o; o >>= 1) { s += __shfl_down(s, o); sq += __shfl_down(sq, o); }
  __shared__ float ss[4], sqs[4];
  if ((tid & 63) == 0) { ss[tid >> 6] = s; sqs[tid >> 6] = sq; }
  __syncthreads();
  s  = ss[0] + ss[1] + ss[2] + ss[3];
  sq = sqs[0] + sqs[1] + sqs[2] + sqs[3];
  float mean = s * (1.f / DM);
  float var  = sq * (1.f / DM) - mean * mean;
  float rstd = rsqrtf(var + 1e-5f);
  float4 gg = ((const float4*)g)[tid];
  float4 bb = ((const float4*)be)[tid];
  float xl[4];
  xl[0] = (v.x - mean) * rstd * gg.x + bb.x;
  xl[1] = (v.y - mean) * rstd * gg.y + bb.y;
  xl[2] = (v.z - mean) * rstd * gg.z + bb.z;
  xl[3] = (v.w - mean) * rstd * gg.w + bb.w;
  ushort4 u;
  u.x = f2bf(xl[0]); u.y = f2bf(xl[1]); u.z = f2bf(xl[2]); u.w = f2bf(xl[3]);
  ((ushort4*)(obf + (size_t)t * DM))[tid] = u;

  float pl[8], pn[8];
  #pragma unroll
  for (int e = 0; e < 8; e++) { pl[e] = 0.f; pn[e] = 0.f; }
  #pragma unroll
  for (int j = 0; j < 4; j++) {
    int d = tid * 4 + j;
    float xv = xl[j];
    const float4* wr = (const float4*)(Wr + (size_t)d * 8);
    const float4* wn = (const float4*)(Wn + (size_t)d * 8);
    float4 a0 = wr[0], a1 = wr[1], c0 = wn[0], c1 = wn[1];
    pl[0] += xv * a0.x; pl[1] += xv * a0.y; pl[2] += xv * a0.z; pl[3] += xv * a0.w;
    pl[4] += xv * a1.x; pl[5] += xv * a1.y; pl[6] += xv * a1.z; pl[7] += xv * a1.w;
    pn[0] += xv * c0.x; pn[1] += xv * c0.y; pn[2] += xv * c0.z; pn[3] += xv * c0.w;
    pn[4] += xv * c1.x; pn[5] += xv * c1.y; pn[6] += xv * c1.z; pn[7] += xv * c1.w;
  }
  for (int o = 32; o; o >>= 1) {
    #pragma unroll
    for (int e = 0; e < 8; e++) { pl[e] += __shfl_down(pl[e], o); pn[e] += __shfl_down(pn[e], o); }
  }
  __shared__ float sl[4][8], sn[4][8];
  if ((tid & 63) == 0) {
    int w = tid >> 6;
    #pragma unroll
    for (int e = 0; e < 8; e++) { sl[w][e] = pl[e]; sn[w][e] = pn[e]; }
  }
  __syncthreads();
  if (tid == 0) {
    float noisy[8];
    #pragma unroll
    for (int e = 0; e < 8; e++) {
      float l  = sl[0][e] + sl[1][e] + sl[2][e] + sl[3][e] + br[e];
      float nn = sn[0][e] + sn[1][e] + sn[2][e] + sn[3][e] + bn[e];
      float sp = (nn > 20.f) ? nn : log1pf(expf(nn));
      noisy[e] = l + noise[(size_t)t * 8 + e] * sp;
    }
    int i0 = 0;
    for (int e = 1; e < 8; e++) if (noisy[e] > noisy[i0]) i0 = e;
    int i1 = (i0 == 0) ? 1 : 0;
    for (int e = 0; e < 8; e++) if (e != i0 && noisy[e] > noisy[i1]) i1 = e;
    float e1 = expf(noisy[i1] - noisy[i0]);
    float zz = 1.f + e1;
    gates[t * 2] = 1.f / zz; gates[t * 2 + 1] = e1 / zz;
    topidx[t * 2] = i0; topidx[t * 2 + 1] = i1;
  }
}

// ---------------- layernorm -> hi/lo bf16 pair (attention path) ----------------
__global__ void k_ln2(const float* __restrict__ in, const float* __restrict__ g,
                      const float* __restrict__ be, u16* __restrict__ oh,
                      u16* __restrict__ ol) {
  int t = blockIdx.x, tid = threadIdx.x;
  float4 v = ((const float4*)(in + (size_t)t * DM))[tid];
  float s = v.x + v.y + v.z + v.w;
  float sq = v.x*v.x + v.y*v.y + v.z*v.z + v.w*v.w;
  for (int o = 32; o; o >>= 1) { s += __shfl_down(s, o); sq += __shfl_down(sq, o); }
  __shared__ float ss[4], sqs[4];
  if ((tid & 63) == 0) { ss[tid >> 6] = s; sqs[tid >> 6] = sq; }
  __syncthreads();
  s  = ss[0] + ss[1] + ss[2] + ss[3];
  sq = sqs[0] + sqs[1] + sqs[2] + sqs[3];
  float mean = s * (1.f / DM);
  float var  = sq * (1.f / DM) - mean * mean;
  float rstd = rsqrtf(var + 1e-5f);
  float4 gg = ((const float4*)g)[tid];
  float4 bb = ((const float4*)be)[tid];
  float o4[4];
  o4[0] = (v.x - mean) * rstd * gg.x + bb.x;
  o4[1] = (v.y - mean) * rstd * gg.y + bb.y;
  o4[2] = (v.z - mean) * rstd * gg.z + bb.z;
  o4[3] = (v.w - mean) * rstd * gg.w + bb.w;
  ushort4 uh, ul;
  u16* ph = (u16*)&uh; u16* pl = (u16*)&ul;
  #pragma unroll
  for (int i = 0; i < 4; i++) {
    u16 hi = f2bf(o4[i]); ph[i] = hi; pl[i] = f2bf(o4[i] - bf2f(hi));
  }
  ((ushort4*)(oh + (size_t)t * DM))[tid] = uh;
  ((ushort4*)(ol + (size_t)t * DM))[tid] = ul;
}

// ---------------- transpose f32 [1024,1024] -> hi/lo bf16, 4 weights batched ----------------
__global__ void k_tcvt_split4(const float* __restrict__ Wq, const float* __restrict__ Wk,
                              const float* __restrict__ Wv, const float* __restrict__ Wo,
                              u16* __restrict__ qkvh, u16* __restrict__ qkvl,
                              u16* __restrict__ oh, u16* __restrict__ ol) {
  __shared__ float t[32][33];
  int z = blockIdx.z;
  const float* src = (z == 0) ? Wq : (z == 1) ? Wk : (z == 2) ? Wv : Wo;
  u16* dh = (z < 3) ? qkvh + (size_t)z * DM * DM : oh;
  u16* dl = (z < 3) ? qkvl + (size_t)z * DM * DM : ol;
  int k0 = blockIdx.x * 32, n0 = blockIdx.y * 32;
  int tx = threadIdx.x, ty = threadIdx.y;
  #pragma unroll
  for (int i = 0; i < 4; i++) t[ty + 8*i][tx] = src[(size_t)(k0 + ty + 8*i) * DM + n0 + tx];
  __syncthreads();
  int u = ty * 32 + tx;
  int r = u >> 3, kq = u & 7;
  ushort4 ohv, olv;
  u16* ph = (u16*)&ohv; u16* pl = (u16*)&olv;
  #pragma unroll
  for (int i = 0; i < 4; i++) {
    float v = t[kq*4+i][r];
    u16 hi = f2bf(v); ph[i] = hi; pl[i] = f2bf(v - bf2f(hi));
  }
  *(ushort4*)&dh[(size_t)(n0 + r) * DM + k0 + kq*4] = ohv;
  *(ushort4*)&dl[(size_t)(n0 + r) * DM + k0 + kq*4] = olv;
}

// ---------------- transpose f32 [K,N] -> bf16 [N,K], 64x64 tiles, 16-expert dual-source ----------------
__global__ void k_tcvt64(const float* __restrict__ srcA, const float* __restrict__ srcB,
                         u16* __restrict__ dst, int K, int N) {
  __shared__ float t[64][65];
  int z = blockIdx.z;
  const float* src = (z < 8) ? srcA + (size_t)z * K * N : srcB + (size_t)(z - 8) * K * N;
  u16* d = dst + (size_t)z * K * N;
  int k0 = blockIdx.x * 64, n0 = blockIdx.y * 64;
  int u = threadIdx.y * 32 + threadIdx.x;
  #pragma unroll
  for (int i = 0; i < 4; i++) {
    int idx = u + i * 256;
    int kr = idx >> 4, nq = (idx & 15) * 4;
    float4 v = *(const float4*)&src[(size_t)(k0 + kr) * N + n0 + nq];
    t[kr][nq] = v.x; t[kr][nq+1] = v.y; t[kr][nq+2] = v.z; t[kr][nq+3] = v.w;
  }
  __syncthreads();
  #pragma unroll
  for (int j = 0; j < 2; j++) {
    int idx = u + j * 256;
    int nr = idx >> 3, kq = (idx & 7) * 8;
    ushort4 o0, o1;
    u16* p0 = (u16*)&o0; u16* p1 = (u16*)&o1;
    #pragma unroll
    for (int i = 0; i < 4; i++) p0[i] = f2bf(t[kq + i][nr]);
    #pragma unroll
    for (int i = 0; i < 4; i++) p1[i] = f2bf(t[kq + 4 + i][nr]);
    *(ushort4*)&d[(size_t)(n0 + nr) * K + k0 + kq]     = o0;
    *(ushort4*)&d[(size_t)(n0 + nr) * K + k0 + kq + 4] = o1;
  }
}

// ---------------- causal softmax f32 -> att hi/lo bf16 in place ----------------
__global__ void k_softmax_h(float* __restrict__ scores) {
  int q = blockIdx.x, bh = blockIdx.y, tid = threadIdx.x;
  float* row = scores + ((size_t)bh * 512 + q) * 512;
  u16* orow = (u16*)row;
  const float scale = 0.088388347648318447f; // 128^-0.5
  int j0 = tid * 2;
  float v0 = -1e30f, v1 = -1e30f;
  if (j0 <= q)     v0 = row[j0] * scale;
  if (j0 + 1 <= q) v1 = row[j0 + 1] * scale;
  float m = fmaxf(v0, v1);
  for (int o = 32; o; o >>= 1) m = fmaxf(m, __shfl_down(m, o));
  __shared__ float sm[4], ssum[4];
  if ((tid & 63) == 0) sm[tid >> 6] = m;
  __syncthreads();
  m = fmaxf(fmaxf(sm[0], sm[1]), fmaxf(sm[2], sm[3]));
  float p0 = (j0 <= q)     ? expf(v0 - m) : 0.f;
  float p1 = (j0 + 1 <= q) ? expf(v1 - m) : 0.f;
  float s = p0 + p1;
  for (int o = 32; o; o >>= 1) s += __shfl_down(s, o);
  if ((tid & 63) == 0) ssum[tid >> 6] = s;
  __syncthreads();
  s = ssum[0] + ssum[1] + ssum[2] + ssum[3];
  float inv = 1.f / s;
  float pi0 = p0 * inv, pi1 = p1 * inv;
  u16 h0 = f2bf(pi0), h1 = f2bf(pi1);
  orow[j0]       = h0; orow[j0 + 1]       = h1;
  orow[512 + j0] = f2bf(pi0 - bf2f(h0));
  orow[512 + j0 + 1] = f2bf(pi1 - bf2f(h1));
}

// ---------------- split-bf16 3-pass MFMA GEMM (attention path) ----------------
constexpr int HOP_QKV    = 0;
constexpr int HOP_SCORES = 1;
constexpr int HOP_PV     = 2;
constexpr int HOP_PROJ   = 3;

struct GemmHArgs {
  const u16 *Ah, *Al, *Bh, *Bl;
  u16 *D0h, *D0l, *D1h, *D1l, *D2h, *D2l;
  float *Cf;
  const float *bias, *resid, *pos;
  int lda, ldb, K;
};

template<int OP>
__launch_bounds__(256, 4)
__global__ void gemm_h(GemmHArgs p) {
  int bx, by, z;
  if constexpr (OP == HOP_QKV) {
    int bid = blockIdx.x; int xcd = bid & 7, slot = bid >> 3;
    by = xcd * 3 + (slot >> 5); bx = slot & 31; z = 0;
  } else if constexpr (OP == HOP_PROJ) {
    int bid = blockIdx.x; by = bid & 7; bx = bid >> 3; z = 0;
  } else if constexpr (OP == HOP_SCORES) { // dense triangular: 10 tiles x 64 bh
    int bid = blockIdx.x; z = bid / 10; int t = bid % 10;
    bx = (t >= 6) ? 3 : (t >= 3) ? 2 : (t >= 1) ? 1 : 0;
    by = t - ((bx * (bx + 1)) >> 1);
  } else {
    bx = blockIdx.x; by = blockIdx.y; z = blockIdx.z;
  }

  const u16 *Ahb, *Alb, *Bhb, *Blb;
  if constexpr (OP == HOP_SCORES) {
    size_t off = (size_t)(z >> 3) * 524288 + (size_t)(z & 7) * 128;
    Ahb = p.Ah + off; Alb = p.Al + off; Bhb = p.Bh + off; Blb = p.Bl + off;
  } else if constexpr (OP == HOP_PV) {
    size_t aoff = (size_t)z * 524288;
    Ahb = p.Ah + aoff; Alb = p.Ah + aoff + 512;
    size_t boff = (size_t)z * 65536;
    Bhb = p.Bh + boff; Blb = p.Bl + boff;
  } else {
    Ahb = p.Ah; Alb = p.Al; Bhb = p.Bh; Blb = p.Bl;
  }

  int kmax = p.K;
  if constexpr (OP == HOP_PV) { int lim = bx * 128 + 128; kmax = lim < p.K ? lim : p.K; }
  int nt = kmax >> 5;

  __shared__ __align__(16) u16 As[2 * 4096];
  __shared__ __align__(16) u16 Bs[2 * 4096];

  int tid = threadIdx.x, lane = tid & 63, wid = tid >> 6;
  int srow = wid * 16 + (lane >> 2), skoff = (lane & 3) * 8;
  int lo0 = (wid * 16) * 32, lo1 = ((wid + 4) * 16) * 32;
  int wr = wid >> 1, wc = wid & 1, fm = lane & 15, fk = (lane >> 4) * 8;

  f32x4 acc[4][4] = {};
  const size_t lda = p.lda, ldb = p.ldb;

  #pragma unroll 1
  for (int pass = 0; pass < 3; ++pass) {
    const u16* Ab = (pass < 2) ? Ahb : Alb;
    const u16* Bb = (pass & 1) ? Blb : Bhb;
    const u16* aptr0 = Ab + (size_t)(bx * 128 + srow) * lda + skoff;
    const u16* aptr1 = Ab + (size_t)(bx * 128 + 64 + srow) * lda + skoff;
    const u16* bptr0 = Bb + (size_t)(by * 128 + srow) * ldb + skoff;
    const u16* bptr1 = Bb + (size_t)(by * 128 + 64 + srow) * ldb + skoff;

    gl_lds16(aptr0, &As[lo0]); gl_lds16(aptr1, &As[lo1]);
    gl_lds16(bptr0, &Bs[lo0]); gl_lds16(bptr1, &Bs[lo1]);
    __syncthreads();
    int cur = 0;
    for (int t = 0; t < nt; ++t) {
      if (t + 1 < nt) {
        int nxt = (cur ^ 1) * 4096;
        int k0 = (t + 1) * 32;
        gl_lds16(aptr0 + k0, &As[nxt + lo0]); gl_lds16(aptr1 + k0, &As[nxt + lo1]);
        gl_lds16(bptr0 + k0, &Bs[nxt + lo0]); gl_lds16(bptr1 + k0, &Bs[nxt + lo1]);
      }
      int cb = cur * 4096;
      bf16x8 af[4], bfr[4];
      #pragma unroll
      for (int i = 0; i < 4; ++i) {
        af[i]  = *(const bf16x8*)&As[cb + (wr * 64 + i * 16 + fm) * 32 + fk];
        bfr[i] = *(const bf16x8*)&Bs[cb + (wc * 64 + i * 16 + fm) * 32 + fk];
      }
      #pragma unroll
      for (int mi = 0; mi < 4; ++mi)
        #pragma unroll
        for (int ni = 0; ni < 4; ++ni)
          acc[mi][ni] = __builtin_amdgcn_mfma_f32_16x16x32_bf16(af[mi], bfr[ni], acc[mi][ni], 0, 0, 0);
      __syncthreads();
      cur ^= 1;
    }
  }

  int rb = (lane >> 4) * 4, cl = lane & 15;
  #pragma unroll
  for (int mi = 0; mi < 4; ++mi)
    #pragma unroll
    for (int ni = 0; ni < 4; ++ni)
      #pragma unroll
      for (int j = 0; j < 4; ++j) {
        int m = bx * 128 + wr * 64 + mi * 16 + rb + j;
        int n = by * 128 + wc * 64 + ni * 16 + cl;
        float v = acc[mi][ni][j];
        if constexpr (OP == HOP_QKV) {
          u16 hi = f2bf(v); u16 lo = f2bf(v - bf2f(hi));
          int sel = n >> 10, nn = n & 1023;
          if (sel == 0) {
            p.D0h[(size_t)m * DM + nn] = hi; p.D0l[(size_t)m * DM + nn] = lo;
          } else if (sel == 1) {
            p.D1h[(size_t)m * DM + nn] = hi; p.D1l[(size_t)m * DM + nn] = lo;
          } else {
            size_t idx = (size_t)((m >> 9) * 8 + (nn >> 7)) * 65536 + (size_t)(nn & 127) * 512 + (m & 511);
            p.D2h[idx] = hi; p.D2l[idx] = lo;
          }
        } else if constexpr (OP == HOP_SCORES) {
          p.Cf[(size_t)z * 262144 + (size_t)m * 512 + n] = v;
        } else if constexpr (OP == HOP_PV) {
          u16 hi = f2bf(v); u16 lo = f2bf(v - bf2f(hi));
          size_t idx = (size_t)(z >> 3) * 524288 + (size_t)m * 1024 + (size_t)(z & 7) * 128 + n;
          p.D0h[idx] = hi; p.D0l[idx] = lo;
        } else { // HOP_PROJ
          size_t idx = (size_t)m * 1024 + n;
          p.Cf[idx] = v + p.bias[n] + p.resid[idx] + p.pos[(size_t)(m & 511) * 1024 + n];
        }
      }
}

// ---------------- bf16 MFMA 128x128 TN GEMM, 2-phase dbuf, 16-expert merged (MoE) ----------------
constexpr int OP_MOE1 = 0; // gathered A rows (joblist -> xlnb[2*TOK]), bf16 C=relu(acc+b1)
constexpr int OP_MOE2 = 1; // contiguous padded A rows, bf16 C=acc+b2

struct GemmArgs {
  const u16* A; const u16* B; void* C;
  const float* b1a; const float* b1b;   // per-half bias arrays (8 experts each)
  const int* joblist; const int* seg;   // seg[0..16]
  int lda, ldb, K;
};

template<int OP>
__launch_bounds__(256)
__global__ void gemm_k(GemmArgs p) {
  int bid = blockIdx.x;
  int xcd = bid & 7, slot = bid >> 3;
  int bx, by;
  if constexpr (OP == OP_MOE1) {
    by = xcd * 4 + (slot & 3);        // grid 4608
    bx = slot >> 2;
  } else {
    bx = xcd * 18 + (slot >> 3);      // grid 1152
    by = slot & 7;
  }
  int r0g = bx * 128;
  if (r0g >= p.seg[16]) return;
  int z = 0;
  #pragma unroll
  for (int e = 1; e < 16; ++e) z += (r0g >= p.seg[e]) ? 1 : 0;
  const u16* Bbase = p.B + (size_t)z * 4194304;
  const float* bias = (z < 8) ? p.b1a + (size_t)z * (OP == OP_MOE1 ? FF : DM)
                              : p.b1b + (size_t)(z - 8) * (OP == OP_MOE1 ? FF : DM);

  __shared__ __align__(16) u16 As[2 * 4096];
  __shared__ __align__(16) u16 Bs[2 * 4096];

  int tid = threadIdx.x;
  int lane = tid & 63, wid = tid >> 6;

  int srow = wid * 16 + (lane >> 2);
  int skoff = (lane & 3) * 8;

  const u16 *aptr0, *aptr1;
  if constexpr (OP == OP_MOE1) {
    int j0 = p.joblist[r0g + srow];
    int j1 = p.joblist[r0g + 64 + srow];
    aptr0 = p.A + (size_t)(j0 < 0 ? 0 : j0) * p.lda + skoff;
    aptr1 = p.A + (size_t)(j1 < 0 ? 0 : j1) * p.lda + skoff;
  } else {
    aptr0 = p.A + (size_t)(r0g + srow) * p.lda + skoff;
    aptr1 = p.A + (size_t)(r0g + 64 + srow) * p.lda + skoff;
  }
  const u16* bptr0 = Bbase + (size_t)(by * 128 + srow) * p.ldb + skoff;
  const u16* bptr1 = Bbase + (size_t)(by * 128 + 64 + srow) * p.ldb + skoff;

  int lo0 = (wid * 16) * 32;
  int lo1 = ((wid + 4) * 16) * 32;

  int wr = wid >> 1, wc = wid & 1;
  int fm = lane & 15;
  int fk = (lane >> 4) * 8;

  f32x4 acc[4][4] = {};
  int nt = p.K >> 5;

  gl_lds16(aptr0, &As[lo0]); gl_lds16(aptr1, &As[lo1]);
  gl_lds16(bptr0, &Bs[lo0]); gl_lds16(bptr1, &Bs[lo1]);
  __syncthreads();

  int cur = 0;
  for (int t = 0; t < nt; ++t) {
    if (t + 1 < nt) {
      int nxt = (cur ^ 1) * 4096;
      int k0 = (t + 1) * 32;
      gl_lds16(aptr0 + k0, &As[nxt + lo0]); gl_lds16(aptr1 + k0, &As[nxt + lo1]);
      gl_lds16(bptr0 + k0, &Bs[nxt + lo0]); gl_lds16(bptr1 + k0, &Bs[nxt + lo1]);
    }
    int cb = cur * 4096;
    bf16x8 af[4], bfr[4];
    #pragma unroll
    for (int i = 0; i < 4; ++i) {
      af[i]  = *(const bf16x8*)&As[cb + (wr * 64 + i * 16 + fm) * 32 + fk];
      bfr[i] = *(const bf16x8*)&Bs[cb + (wc * 64 + i * 16 + fm) * 32 + fk];
    }
    #pragma unroll
    for (int mi = 0; mi < 4; ++mi)
      #pragma unroll
      for (int ni = 0; ni < 4; ++ni)
        acc[mi][ni] = __builtin_amdgcn_mfma_f32_16x16x32_bf16(af[mi], bfr[ni], acc[mi][ni], 0, 0, 0);
    __syncthreads();
    cur ^= 1;
  }

  int rb = (lane >> 4) * 4;
  int cl = lane & 15;
  #pragma unroll
  for (int mi = 0; mi < 4; ++mi)
    #pragma unroll
    for (int ni = 0; ni < 4; ++ni)
      #pragma unroll
      for (int j = 0; j < 4; ++j) {
        int m = r0g + wr * 64 + mi * 16 + rb + j;
        int n = by * 128 + wc * 64 + ni * 16 + cl;
        float v = acc[mi][ni][j] + bias[n];
        if constexpr (OP == OP_MOE1) {
          v = v > 0.f ? v : 0.f;
          ((u16*)p.C)[(size_t)m * FF + n] = f2bf(v);
        } else {
          ((u16*)p.C)[(size_t)m * DM + n] = f2bf(v);
        }
      }
}

// ---------------- MoE bookkeeping (16-expert merged) ----------------
__global__ void k_moe_init(int* cnt, int* cnt2, int* joblist) {
  int i = blockIdx.x * 256 + threadIdx.x;
  if (i < JOBCAP) joblist[i] = -1;
  if (i < 16) { cnt[i] = 0; cnt2[i] = 0; }
}
__global__ void k_moe_count(const int* __restrict__ topidx, int* __restrict__ cnt) {
  int t = blockIdx.x * 256 + threadIdx.x;     // global token 0..2*TOK
  if (t >= 2 * TOK) return;
  int lo = (t >= TOK) ? 8 : 0;
  atomicAdd(&cnt[topidx[t * 2] + lo], 1);
  atomicAdd(&cnt[topidx[t * 2 + 1] + lo], 1);
}
__global__ void k_moe_offsets(const int* __restrict__ cnt, int* __restrict__ seg) {
  if (threadIdx.x == 0) {
    int o = 0;
    for (int e = 0; e < 16; e++) { seg[e] = o; o += (cnt[e] + 127) & ~127; }
    seg[16] = o;
  }
}
__global__ void k_moe_scatter(const int* __restrict__ topidx, int* __restrict__ cnt2,
                              const int* __restrict__ seg, int* __restrict__ joblist,
                              int* __restrict__ tokpos) {
  int t = blockIdx.x * 256 + threadIdx.x;
  if (t >= 2 * TOK) return;
  int lo = (t >= TOK) ? 8 : 0;
  #pragma unroll
  for (int s = 0; s < 2; s++) {
    int e = topidx[t * 2 + s] + lo;
    int p = atomicAdd(&cnt2[e], 1);
    int pos = seg[e] + p;
    joblist[pos] = t;                 // global row into xlnb[2*TOK]
    tokpos[t * 2 + s] = pos;
  }
}
__global__ void k_combine(const u16* __restrict__ y, const float* __restrict__ gates,
                          const int* __restrict__ tokpos, float* __restrict__ out) {
  int t = blockIdx.x, tid = threadIdx.x;
  int p0 = tokpos[t * 2], p1 = tokpos[t * 2 + 1];
  float g0 = gates[t * 2], g1 = gates[t * 2 + 1];
  ushort4 a = ((const ushort4*)(y + (size_t)p0 * DM))[tid];
  ushort4 b = ((const ushort4*)(y + (size_t)p1 * DM))[tid];
  float4 o;
  o.x = g0 * bf2f(a.x) + g1 * bf2f(b.x);
  o.y = g0 * bf2f(a.y) + g1 * bf2f(b.y);
  o.z = g0 * bf2f(a.z) + g1 * bf2f(b.z);
  o.w = g0 * bf2f(a.w) + g1 * bf2f(b.w);
  ((float4*)(out + (size_t)t * DM))[tid] = o;
}

// ---------------- feature mean (two-stage) + classifier ----------------
__global__ void k_feat1(const float* __restrict__ second, float* __restrict__ part) {
  int b = blockIdx.x, c = blockIdx.y, tid = threadIdx.x;
  const float* p = second + ((size_t)b * SEQ + (size_t)c * 64) * DM;
  float4 s = {0.f, 0.f, 0.f, 0.f};
  for (int j = 0; j < 64; ++j) {
    float4 v = ((const float4*)(p + (size_t)j * DM))[tid];
    s.x += v.x; s.y += v.y; s.z += v.z; s.w += v.w;
  }
  ((float4*)(part + (size_t)(b * 8 + c) * DM))[tid] = s;
}
__global__ void k_feat2(const float* __restrict__ part, float* __restrict__ feat) {
  int i = blockIdx.x * 256 + threadIdx.x;
  int b = i >> 10, d = i & 1023;
  float s = 0.f;
  #pragma unroll
  for (int c = 0; c < 8; ++c) s += part[(size_t)(b * 8 + c) * DM + d];
  feat[i] = s * (1.f / SEQ);
}
__global__ void k_cls(const float* __restrict__ feat, const float* __restrict__ Wc,
                      const float* __restrict__ bc, float* __restrict__ cls) {
  int o = blockIdx.x; int b = o / 10, n = o % 10; int l = threadIdx.x;
  float s = 0.f;
  for (int d = l; d < DM; d += 64) s += feat[b * DM + d] * Wc[(size_t)d * 10 + n];
  for (int off = 32; off; off >>= 1) s += __shfl_down(s, off);
  if (l == 0) cls[o] = s + bc[n];
}

// ---------------- launch ----------------
extern "C" void kernel_launch(void* const* d_in, const int* in_sizes, int n_in,
                              void* d_out, int out_size, void* d_ws, size_t ws_size,
                              hipStream_t stream) {
  const int*   ids    = (const int*)d_in[0];
  const float* emb    = (const float*)d_in[2];
  const float* pos    = (const float*)d_in[3];
  const float* Wq     = (const float*)d_in[4];
  const float* Wk     = (const float*)d_in[5];
  const float* Wv     = (const float*)d_in[6];
  const float* Wo     = (const float*)d_in[7];
  const float* bo     = (const float*)d_in[8];
  const float* g1     = (const float*)d_in[9];
  const float* be1    = (const float*)d_in[10];
  const float* g2     = (const float*)d_in[11];
  const float* be2    = (const float*)d_in[12];
  const float* g3     = (const float*)d_in[13];
  const float* be3    = (const float*)d_in[14];
  const float* Wr1    = (const float*)d_in[15];
  const float* br1    = (const float*)d_in[16];
  const float* Wn1    = (const float*)d_in[17];
  const float* bn1    = (const float*)d_in[18];
  const float* W1a    = (const float*)d_in[19];
  const float* b1a    = (const float*)d_in[20];
  const float* W2a    = (const float*)d_in[21];
  const float* b2a    = (const float*)d_in[22];
  const float* Wr2    = (const float*)d_in[23];
  const float* br2    = (const float*)d_in[24];
  const float* Wn2    = (const float*)d_in[25];
  const float* bn2    = (const float*)d_in[26];
  const float* W1b    = (const float*)d_in[27];
  const float* b1b    = (const float*)d_in[28];
  const float* W2b    = (const float*)d_in[29];
  const float* b2b    = (const float*)d_in[30];
  const float* noise1 = (const float*)d_in[31];
  const float* noise2 = (const float*)d_in[32];
  const float* Wc     = (const float*)d_in[33];
  const float* bc     = (const float*)d_in[34];

  char* wsp = (char*)d_ws; size_t off = 0;
  auto alloc = [&](size_t bytes) -> void* {
    void* p = wsp + off; off += (bytes + 255) & ~(size_t)255; return p;
  };
  char*  G     = (char*)alloc(360710144);              // phase-overlaid big region (344MB)
  float* x     = (float*)alloc((size_t)TOK * DM * 4);
  float* x2    = (float*)alloc((size_t)TOK * DM * 4);
  u16*   xlnb  = (u16*)alloc((size_t)2 * TOK * DM * 2);   // both layers' LN
  float* gates  = (float*)alloc(2 * TOK * 2 * 4);
  int*   topidx = (int*)alloc(2 * TOK * 2 * 4);
  int*   cnt    = (int*)alloc(16 * 4);
  int*   cnt2   = (int*)alloc(16 * 4);
  int*   seg    = (int*)alloc(24 * 4);
  int*   joblist= (int*)alloc(JOBCAP * 4);
  int*   tokpos = (int*)alloc(2 * TOK * 2 * 4);
  float* fpart  = (float*)alloc(64 * DM * 4);
  (void)ws_size; (void)in_sizes; (void)n_in; (void)out_size;

  // attention-phase views (~164MB of G)
  u16* WQKVTh = (u16*)(G + 0);
  u16* WQKVTl = (u16*)(G + 6291456);
  u16* WOTh   = (u16*)(G + 12582912);
  u16* WOTl   = (u16*)(G + 14680064);
  u16* XLNH   = (u16*)(G + 16777216);
  u16* XLNL   = (u16*)(G + 25165824);
  u16* QH     = (u16*)(G + 33554432);
  u16* QL     = (u16*)(G + 41943040);
  u16* KH     = (u16*)(G + 50331648);
  u16* KL     = (u16*)(G + 58720256);
  u16* VTh    = (u16*)(G + 67108864);
  u16* VTl    = (u16*)(G + 75497472);
  u16* OH     = (u16*)(G + 83886080);
  u16* OL     = (u16*)(G + 92274688);
  float* SC   = (float*)(G + 100663296);  // [64][512][512] f32 -> att hi/lo in place
  // moe-phase views (G; attention buffers dead by then)
  u16*   H    = (u16*)(G + 0);            // [18432][4096] bf16 (151MB)
  u16*   Y    = (u16*)(G + 150994944);    // [18432][1024] bf16 (37.7MB)
  u16*   WBUF = (u16*)(G + 226492416);    // 16 experts' weights bf16 (128MB)

  float* out_first  = (float*)d_out;
  float* out_second = out_first + (size_t)TOK * DM;
  float* feat       = out_first + (size_t)2 * TOK * DM;
  float* cls        = feat + 8 * DM;

  dim3 tb(32, 8);
  // ---- attention phase: split-bf16 3-pass ----
  hipLaunchKernelGGL(k_tcvt_split4, dim3(32, 32, 4), tb, 0, stream, Wq, Wk, Wv, Wo,
                     WQKVTh, WQKVTl, WOTh, WOTl);
  hipLaunchKernelGGL(k_embed, dim3(TOK), dim3(256), 0, stream, ids, emb, x);
  hipLaunchKernelGGL(k_ln2, dim3(TOK), dim3(256), 0, stream, x, g1, be1, XLNH, XLNL);

  GemmHArgs qa{};
  qa.Ah = XLNH; qa.Al = XLNL; qa.Bh = WQKVTh; qa.Bl = WQKVTl;
  qa.D0h = QH; qa.D0l = QL; qa.D1h = KH; qa.D1l = KL; qa.D2h = VTh; qa.D2l = VTl;
  qa.lda = DM; qa.ldb = DM; qa.K = DM;
  hipLaunchKernelGGL(gemm_h<HOP_QKV>, dim3(768), dim3(256), 0, stream, qa);

  GemmHArgs sa{};
  sa.Ah = QH; sa.Al = QL; sa.Bh = KH; sa.Bl = KL; sa.Cf = SC;
  sa.lda = DM; sa.ldb = DM; sa.K = HD;
  hipLaunchKernelGGL(gemm_h<HOP_SCORES>, dim3(640), dim3(256), 0, stream, sa);
  hipLaunchKernelGGL(k_softmax_h, dim3(SEQ, 64), dim3(256), 0, stream, SC);

  GemmHArgs pa{};
  pa.Ah = (const u16*)SC; pa.Bh = VTh; pa.Bl = VTl;
  pa.D0h = OH; pa.D0l = OL;
  pa.lda = 1024; pa.ldb = 512; pa.K = SEQ;
  hipLaunchKernelGGL(gemm_h<HOP_PV>, dim3(4, 1, 64), dim3(256), 0, stream, pa);

  GemmHArgs pj{};
  pj.Ah = OH; pj.Al = OL; pj.Bh = WOTh; pj.Bl = WOTl; pj.Cf = x2;
  pj.bias = bo; pj.resid = x; pj.pos = pos;
  pj.lda = DM; pj.ldb = DM; pj.K = DM;
  hipLaunchKernelGGL(gemm_h<HOP_PROJ>, dim3(256), dim3(256), 0, stream, pj);

  // ---- MoE phase: both layers merged into one 16-expert batch ----
  hipLaunchKernelGGL(k_lnrouter, dim3(TOK), dim3(256), 0, stream, x2, g2, be2,
                     Wr1, br1, Wn1, bn1, noise1, xlnb, gates, topidx);
  hipLaunchKernelGGL(k_lnrouter, dim3(TOK), dim3(256), 0, stream, x2, g3, be3,
                     Wr2, br2, Wn2, bn2, noise2, xlnb + (size_t)TOK * DM,
                     gates + (size_t)TOK * 2, topidx + (size_t)TOK * 2);
  hipLaunchKernelGGL(k_moe_init, dim3(72), dim3(256), 0, stream, cnt, cnt2, joblist);
  hipLaunchKernelGGL(k_moe_count, dim3(32), dim3(256), 0, stream, topidx, cnt);
  hipLaunchKernelGGL(k_moe_offsets, dim3(1), dim3(64), 0, stream, cnt, seg);
  hipLaunchKernelGGL(k_moe_scatter, dim3(32), dim3(256), 0, stream, topidx, cnt2, seg, joblist, tokpos);

  hipLaunchKernelGGL(k_tcvt64, dim3(16, 64, 16), tb, 0, stream, W1a, W1b, WBUF, DM, FF);
  GemmArgs m1{};
  m1.A = xlnb; m1.B = WBUF; m1.C = H; m1.b1a = b1a; m1.b1b = b1b;
  m1.joblist = joblist; m1.seg = seg;
  m1.lda = DM; m1.ldb = DM; m1.K = DM;
  hipLaunchKernelGGL(gemm_k<OP_MOE1>, dim3(4608), dim3(256), 0, stream, m1);

  hipLaunchKernelGGL(k_tcvt64, dim3(64, 16, 16), tb, 0, stream, W2a, W2b, WBUF, FF, DM);
  GemmArgs m2{};
  m2.A = H; m2.B = WBUF; m2.C = Y; m2.b1a = b2a; m2.b1b = b2b;
  m2.joblist = joblist; m2.seg = seg;
  m2.lda = FF; m2.ldb = FF; m2.K = FF;
  hipLaunchKernelGGL(gemm_k<OP_MOE2>, dim3(1152), dim3(256), 0, stream, m2);

  hipLaunchKernelGGL(k_combine, dim3(TOK), dim3(256), 0, stream, Y, gates, tokpos, out_first);
  hipLaunchKernelGGL(k_combine, dim3(TOK), dim3(256), 0, stream, Y,
                     gates + (size_t)TOK * 2, tokpos + (size_t)TOK * 2, out_second);

  hipLaunchKernelGGL(k_feat1, dim3(8, 8), dim3(256), 0, stream, out_second, fpart);
  hipLaunchKernelGGL(k_feat2, dim3(32), dim3(256), 0, stream, fpart, feat);
  hipLaunchKernelGGL(k_cls, dim3(80), dim3(64), 0, stream, feat, Wc, bc, cls);
}

// Round 16
// 1116.042 us; speedup vs baseline: 1.0896x; 1.0083x over previous
//
#include <hip/hip_runtime.h>
#include <cstdint>

typedef unsigned short u16;
typedef __attribute__((ext_vector_type(8))) __bf16 bf16x8;
typedef __attribute__((ext_vector_type(4))) float f32x4;

#define TOK 4096
#define DM  1024
#define EXP 8
#define FF  4096
#define SEQ 512
#define NH  8
#define HD  128
#define JOBCAP 18432

__device__ __forceinline__ u16 f2bf(float f) {
  union { float f; unsigned int u; } v; v.f = f;
  unsigned int u = v.u;
  u += 0x7FFFu + ((u >> 16) & 1u);   // round-to-nearest-even
  return (u16)(u >> 16);
}
__device__ __forceinline__ float bf2f(u16 h) {
  union { unsigned int u; float f; } v; v.u = ((unsigned int)h) << 16; return v.f;
}

// async global->LDS, 16B per lane; dest = wave-uniform base + lane*16
__device__ __forceinline__ void gl_lds16(const u16* g, u16* l) {
  __builtin_amdgcn_global_load_lds(
      (const __attribute__((address_space(1))) unsigned int*)g,
      (__attribute__((address_space(3))) unsigned int*)l, 16, 0, 0);
}

// ---------------- embed gather ----------------
__global__ void k_embed(const int* __restrict__ ids, const float* __restrict__ emb,
                        float* __restrict__ x) {
  int t = blockIdx.x;
  int id = ids[t];
  const float4* src = (const float4*)(emb + (size_t)id * DM);
  float4* dst = (float4*)(x + (size_t)t * DM);
  dst[threadIdx.x] = src[threadIdx.x];
}

// ---------------- fused layernorm(bf16 out) + router (MoE path) ----------------
__global__ void k_lnrouter(const float* __restrict__ xin, const float* __restrict__ g,
                           const float* __restrict__ be,
                           const float* __restrict__ Wr, const float* __restrict__ br,
                           const float* __restrict__ Wn, const float* __restrict__ bn,
                           const float* __restrict__ noise,
                           u16* __restrict__ obf,
                           float* __restrict__ gates, int* __restrict__ topidx) {
  int t = blockIdx.x, tid = threadIdx.x;
  float4 v = ((const float4*)(xin + (size_t)t * DM))[tid];
  float s = v.x + v.y + v.z + v.w;
  float sq = v.x*v.x + v.y*v.y + v.z*v.z + v.w*v.w;
  for (int o = 32; o; o >>= 1) { s += __shfl_down(s, o); sq += __shfl_down(sq, o); }
  __shared__ float ss[4], sqs[4];
  if ((tid & 63) == 0) { ss[tid >> 6] = s; sqs[tid >> 6] = sq; }
  __syncthreads();
  s  = ss[0] + ss[1] + ss[2] + ss[3];
  sq = sqs[0] + sqs[1] + sqs[2] + sqs[3];
  float mean = s * (1.f / DM);
  float var  = sq * (1.f / DM) - mean * mean;
  float rstd = rsqrtf(var + 1e-5f);
  float4 gg = ((const float4*)g)[tid];
  float4 bb = ((const float4*)be)[tid];
  float xl[4];
  xl[0] = (v.x - mean) * rstd * gg.x + bb.x;
  xl[1] = (v.y - mean) * rstd * gg.y + bb.y;
  xl[2] = (v.z - mean) * rstd * gg.z + bb.z;
  xl[3] = (v.w - mean) * rstd * gg.w + bb.w;
  ushort4 u;
  u.x = f2bf(xl[0]); u.y = f2bf(xl[1]); u.z = f2bf(xl[2]); u.w = f2bf(xl[3]);
  ((ushort4*)(obf + (size_t)t * DM))[tid] = u;

  float pl[8], pn[8];
  #pragma unroll
  for (int e = 0; e < 8; e++) { pl[e] = 0.f; pn[e] = 0.f; }
  #pragma unroll
  for (int j = 0; j < 4; j++) {
    int d = tid * 4 + j;
    float xv = xl[j];
    const float4* wr = (const float4*)(Wr + (size_t)d * 8);
    const float4* wn = (const float4*)(Wn + (size_t)d * 8);
    float4 a0 = wr[0], a1 = wr[1], c0 = wn[0], c1 = wn[1];
    pl[0] += xv * a0.x; pl[1] += xv * a0.y; pl[2] += xv * a0.z; pl[3] += xv * a0.w;
    pl[4] += xv * a1.x; pl[5] += xv * a1.y; pl[6] += xv * a1.z; pl[7] += xv * a1.w;
    pn[0] += xv * c0.x; pn[1] += xv * c0.y; pn[2] += xv * c0.z; pn[3] += xv * c0.w;
    pn[4] += xv * c1.x; pn[5] += xv * c1.y; pn[6] += xv * c1.z; pn[7] += xv * c1.w;
  }
  for (int o = 32; o; o >>= 1) {
    #pragma unroll
    for (int e = 0; e < 8; e++) { pl[e] += __shfl_down(pl[e], o); pn[e] += __shfl_down(pn[e], o); }
  }
  __shared__ float sl[4][8], sn[4][8];
  if ((tid & 63) == 0) {
    int w = tid >> 6;
    #pragma unroll
    for (int e = 0; e < 8; e++) { sl[w][e] = pl[e]; sn[w][e] = pn[e]; }
  }
  __syncthreads();
  if (tid == 0) {
    float noisy[8];
    #pragma unroll
    for (int e = 0; e < 8; e++) {
      float l  = sl[0][e] + sl[1][e] + sl[2][e] + sl[3][e] + br[e];
      float nn = sn[0][e] + sn[1][e] + sn[2][e] + sn[3][e] + bn[e];
      float sp = (nn > 20.f) ? nn : log1pf(expf(nn));
      noisy[e] = l + noise[(size_t)t * 8 + e] * sp;
    }
    int i0 = 0;
    for (int e = 1; e < 8; e++) if (noisy[e] > noisy[i0]) i0 = e;
    int i1 = (i0 == 0) ? 1 : 0;
    for (int e = 0; e < 8; e++) if (e != i0 && noisy[e] > noisy[i1]) i1 = e;
    float e1 = expf(noisy[i1] - noisy[i0]);
    float zz = 1.f + e1;
    gates[t * 2] = 1.f / zz; gates[t * 2 + 1] = e1 / zz;
    topidx[t * 2] = i0; topidx[t * 2 + 1] = i1;
  }
}

// ---------------- layernorm -> hi/lo bf16 pair (attention path) ----------------
__global__ void k_ln2(const float* __restrict__ in, const float* __restrict__ g,
                      const float* __restrict__ be, u16* __restrict__ oh,
                      u16* __restrict__ ol) {
  int t = blockIdx.x, tid = threadIdx.x;
  float4 v = ((const float4*)(in + (size_t)t * DM))[tid];
  float s = v.x + v.y + v.z + v.w;
  float sq = v.x*v.x + v.y*v.y + v.z*v.z + v.w*v.w;
  for (int o = 32; o; o >>= 1) { s += __shfl_down(s, o); sq += __shfl_down(sq, o); }
  __shared__ float ss[4], sqs[4];
  if ((tid & 63) == 0) { ss[tid >> 6] = s; sqs[tid >> 6] = sq; }
  __syncthreads();
  s  = ss[0] + ss[1] + ss[2] + ss[3];
  sq = sqs[0] + sqs[1] + sqs[2] + sqs[3];
  float mean = s * (1.f / DM);
  float var  = sq * (1.f / DM) - mean * mean;
  float rstd = rsqrtf(var + 1e-5f);
  float4 gg = ((const float4*)g)[tid];
  float4 bb = ((const float4*)be)[tid];
  float o4[4];
  o4[0] = (v.x - mean) * rstd * gg.x + bb.x;
  o4[1] = (v.y - mean) * rstd * gg.y + bb.y;
  o4[2] = (v.z - mean) * rstd * gg.z + bb.z;
  o4[3] = (v.w - mean) * rstd * gg.w + bb.w;
  ushort4 uh, ul;
  u16* ph = (u16*)&uh; u16* pl = (u16*)&ul;
  #pragma unroll
  for (int i = 0; i < 4; i++) {
    u16 hi = f2bf(o4[i]); ph[i] = hi; pl[i] = f2bf(o4[i] - bf2f(hi));
  }
  ((ushort4*)(oh + (size_t)t * DM))[tid] = uh;
  ((ushort4*)(ol + (size_t)t * DM))[tid] = ul;
}

// ---------------- transpose f32 [1024,1024] -> hi/lo bf16, 4 weights batched ----------------
__global__ void k_tcvt_split4(const float* __restrict__ Wq, const float* __restrict__ Wk,
                              const float* __restrict__ Wv, const float* __restrict__ Wo,
                              u16* __restrict__ qkvh, u16* __restrict__ qkvl,
                              u16* __restrict__ oh, u16* __restrict__ ol) {
  __shared__ float t[32][33];
  int z = blockIdx.z;
  const float* src = (z == 0) ? Wq : (z == 1) ? Wk : (z == 2) ? Wv : Wo;
  u16* dh = (z < 3) ? qkvh + (size_t)z * DM * DM : oh;
  u16* dl = (z < 3) ? qkvl + (size_t)z * DM * DM : ol;
  int k0 = blockIdx.x * 32, n0 = blockIdx.y * 32;
  int tx = threadIdx.x, ty = threadIdx.y;
  #pragma unroll
  for (int i = 0; i < 4; i++) t[ty + 8*i][tx] = src[(size_t)(k0 + ty + 8*i) * DM + n0 + tx];
  __syncthreads();
  int u = ty * 32 + tx;
  int r = u >> 3, kq = u & 7;
  ushort4 ohv, olv;
  u16* ph = (u16*)&ohv; u16* pl = (u16*)&olv;
  #pragma unroll
  for (int i = 0; i < 4; i++) {
    float v = t[kq*4+i][r];
    u16 hi = f2bf(v); ph[i] = hi; pl[i] = f2bf(v - bf2f(hi));
  }
  *(ushort4*)&dh[(size_t)(n0 + r) * DM + k0 + kq*4] = ohv;
  *(ushort4*)&dl[(size_t)(n0 + r) * DM + k0 + kq*4] = olv;
}

// ---------------- transpose f32 [K,N] -> bf16 [N,K], 64x64 tiles, 16-expert dual-source ----------------
__global__ void k_tcvt64(const float* __restrict__ srcA, const float* __restrict__ srcB,
                         u16* __restrict__ dst, int K, int N) {
  __shared__ float t[64][65];
  int z = blockIdx.z;
  const float* src = (z < 8) ? srcA + (size_t)z * K * N : srcB + (size_t)(z - 8) * K * N;
  u16* d = dst + (size_t)z * K * N;
  int k0 = blockIdx.x * 64, n0 = blockIdx.y * 64;
  int u = threadIdx.y * 32 + threadIdx.x;
  #pragma unroll
  for (int i = 0; i < 4; i++) {
    int idx = u + i * 256;
    int kr = idx >> 4, nq = (idx & 15) * 4;
    float4 v = *(const float4*)&src[(size_t)(k0 + kr) * N + n0 + nq];
    t[kr][nq] = v.x; t[kr][nq+1] = v.y; t[kr][nq+2] = v.z; t[kr][nq+3] = v.w;
  }
  __syncthreads();
  #pragma unroll
  for (int j = 0; j < 2; j++) {
    int idx = u + j * 256;
    int nr = idx >> 3, kq = (idx & 7) * 8;
    ushort4 o0, o1;
    u16* p0 = (u16*)&o0; u16* p1 = (u16*)&o1;
    #pragma unroll
    for (int i = 0; i < 4; i++) p0[i] = f2bf(t[kq + i][nr]);
    #pragma unroll
    for (int i = 0; i < 4; i++) p1[i] = f2bf(t[kq + 4 + i][nr]);
    *(ushort4*)&d[(size_t)(n0 + nr) * K + k0 + kq]     = o0;
    *(ushort4*)&d[(size_t)(n0 + nr) * K + k0 + kq + 4] = o1;
  }
}

// ---------------- causal softmax f32 -> att hi/lo bf16 in place ----------------
__global__ void k_softmax_h(float* __restrict__ scores) {
  int q = blockIdx.x, bh = blockIdx.y, tid = threadIdx.x;
  float* row = scores + ((size_t)bh * 512 + q) * 512;
  u16* orow = (u16*)row;
  const float scale = 0.088388347648318447f; // 128^-0.5
  int j0 = tid * 2;
  float v0 = -1e30f, v1 = -1e30f;
  if (j0 <= q)     v0 = row[j0] * scale;
  if (j0 + 1 <= q) v1 = row[j0 + 1] * scale;
  float m = fmaxf(v0, v1);
  for (int o = 32; o; o >>= 1) m = fmaxf(m, __shfl_down(m, o));
  __shared__ float sm[4], ssum[4];
  if ((tid & 63) == 0) sm[tid >> 6] = m;
  __syncthreads();
  m = fmaxf(fmaxf(sm[0], sm[1]), fmaxf(sm[2], sm[3]));
  float p0 = (j0 <= q)     ? expf(v0 - m) : 0.f;
  float p1 = (j0 + 1 <= q) ? expf(v1 - m) : 0.f;
  float s = p0 + p1;
  for (int o = 32; o; o >>= 1) s += __shfl_down(s, o);
  if ((tid & 63) == 0) ssum[tid >> 6] = s;
  __syncthreads();
  s = ssum[0] + ssum[1] + ssum[2] + ssum[3];
  float inv = 1.f / s;
  float pi0 = p0 * inv, pi1 = p1 * inv;
  u16 h0 = f2bf(pi0), h1 = f2bf(pi1);
  orow[j0]       = h0; orow[j0 + 1]       = h1;
  orow[512 + j0] = f2bf(pi0 - bf2f(h0));
  orow[512 + j0 + 1] = f2bf(pi1 - bf2f(h1));
}

// ---------------- split-bf16 FUSED 3-term MFMA GEMM (attention path) ----------------
// Per K-step stage Ah/Al/Bh/Bl tiles ONCE (2-buffered, 64KB LDS) and issue all
// 48 MFMAs (ah*bh + ah*bl + al*bh). Same math as 3 sequential passes; staging
// traffic x2/3, barriers x1/3.
constexpr int HOP_QKV    = 0;
constexpr int HOP_SCORES = 1;
constexpr int HOP_PV     = 2;
constexpr int HOP_PROJ   = 3;

struct GemmHArgs {
  const u16 *Ah, *Al, *Bh, *Bl;
  u16 *D0h, *D0l, *D1h, *D1l, *D2h, *D2l;
  float *Cf;
  const float *bias, *resid, *pos;
  int lda, ldb, K;
};

template<int OP>
__launch_bounds__(256)
__global__ void gemm_h(GemmHArgs p) {
  int bx, by, z;
  if constexpr (OP == HOP_QKV) {
    int bid = blockIdx.x; int xcd = bid & 7, slot = bid >> 3;
    by = xcd * 3 + (slot >> 5); bx = slot & 31; z = 0;
  } else if constexpr (OP == HOP_PROJ) {
    int bid = blockIdx.x; by = bid & 7; bx = bid >> 3; z = 0;
  } else if constexpr (OP == HOP_SCORES) { // dense triangular: 10 tiles x 64 bh
    int bid = blockIdx.x; z = bid / 10; int t = bid % 10;
    bx = (t >= 6) ? 3 : (t >= 3) ? 2 : (t >= 1) ? 1 : 0;
    by = t - ((bx * (bx + 1)) >> 1);
  } else {
    bx = blockIdx.x; by = blockIdx.y; z = blockIdx.z;
  }

  const u16 *Ahb, *Alb, *Bhb, *Blb;
  if constexpr (OP == HOP_SCORES) {
    size_t off = (size_t)(z >> 3) * 524288 + (size_t)(z & 7) * 128;
    Ahb = p.Ah + off; Alb = p.Al + off; Bhb = p.Bh + off; Blb = p.Bl + off;
  } else if constexpr (OP == HOP_PV) {
    size_t aoff = (size_t)z * 524288;
    Ahb = p.Ah + aoff; Alb = p.Ah + aoff + 512;
    size_t boff = (size_t)z * 65536;
    Bhb = p.Bh + boff; Blb = p.Bl + boff;
  } else {
    Ahb = p.Ah; Alb = p.Al; Bhb = p.Bh; Blb = p.Bl;
  }

  int kmax = p.K;
  if constexpr (OP == HOP_PV) { int lim = bx * 128 + 128; kmax = lim < p.K ? lim : p.K; }
  int nt = kmax >> 5;

  __shared__ __align__(16) u16 Ahs[2 * 4096];
  __shared__ __align__(16) u16 Als[2 * 4096];
  __shared__ __align__(16) u16 Bhs[2 * 4096];
  __shared__ __align__(16) u16 Bls[2 * 4096];

  int tid = threadIdx.x, lane = tid & 63, wid = tid >> 6;
  int srow = wid * 16 + (lane >> 2), skoff = (lane & 3) * 8;
  int lo0 = (wid * 16) * 32, lo1 = ((wid + 4) * 16) * 32;
  int wr = wid >> 1, wc = wid & 1, fm = lane & 15, fk = (lane >> 4) * 8;

  const size_t lda = p.lda, ldb = p.ldb;
  size_t ar0 = (size_t)(bx * 128 + srow) * lda + skoff;
  size_t ar1 = (size_t)(bx * 128 + 64 + srow) * lda + skoff;
  size_t br0 = (size_t)(by * 128 + srow) * ldb + skoff;
  size_t br1 = (size_t)(by * 128 + 64 + srow) * ldb + skoff;

  f32x4 acc[4][4] = {};

#define STAGE_H(BUF, K0) { int _b = (BUF) * 4096;                          \
    gl_lds16(Ahb + ar0 + (K0), &Ahs[_b + lo0]); gl_lds16(Ahb + ar1 + (K0), &Ahs[_b + lo1]); \
    gl_lds16(Alb + ar0 + (K0), &Als[_b + lo0]); gl_lds16(Alb + ar1 + (K0), &Als[_b + lo1]); \
    gl_lds16(Bhb + br0 + (K0), &Bhs[_b + lo0]); gl_lds16(Bhb + br1 + (K0), &Bhs[_b + lo1]); \
    gl_lds16(Blb + br0 + (K0), &Bls[_b + lo0]); gl_lds16(Blb + br1 + (K0), &Bls[_b + lo1]); }

  STAGE_H(0, 0);
  __syncthreads();
  int cur = 0;
  for (int t = 0; t < nt; ++t) {
    if (t + 1 < nt) STAGE_H(cur ^ 1, (t + 1) * 32);
    int cb = cur * 4096;
    bf16x8 ah[4], al_[4], bh[4], bl[4];
    #pragma unroll
    for (int i = 0; i < 4; ++i) {
      int ao = cb + (wr * 64 + i * 16 + fm) * 32 + fk;
      int bo = cb + (wc * 64 + i * 16 + fm) * 32 + fk;
      ah[i]  = *(const bf16x8*)&Ahs[ao];
      bh[i]  = *(const bf16x8*)&Bhs[bo];
      al_[i] = *(const bf16x8*)&Als[ao];
      bl[i]  = *(const bf16x8*)&Bls[bo];
    }
    #pragma unroll
    for (int mi = 0; mi < 4; ++mi)
      #pragma unroll
      for (int ni = 0; ni < 4; ++ni)
        acc[mi][ni] = __builtin_amdgcn_mfma_f32_16x16x32_bf16(ah[mi], bh[ni], acc[mi][ni], 0, 0, 0);
    #pragma unroll
    for (int mi = 0; mi < 4; ++mi)
      #pragma unroll
      for (int ni = 0; ni < 4; ++ni)
        acc[mi][ni] = __builtin_amdgcn_mfma_f32_16x16x32_bf16(ah[mi], bl[ni], acc[mi][ni], 0, 0, 0);
    #pragma unroll
    for (int mi = 0; mi < 4; ++mi)
      #pragma unroll
      for (int ni = 0; ni < 4; ++ni)
        acc[mi][ni] = __builtin_amdgcn_mfma_f32_16x16x32_bf16(al_[mi], bh[ni], acc[mi][ni], 0, 0, 0);
    __syncthreads();
    cur ^= 1;
  }
#undef STAGE_H

  int rb = (lane >> 4) * 4, cl = lane & 15;
  #pragma unroll
  for (int mi = 0; mi < 4; ++mi)
    #pragma unroll
    for (int ni = 0; ni < 4; ++ni)
      #pragma unroll
      for (int j = 0; j < 4; ++j) {
        int m = bx * 128 + wr * 64 + mi * 16 + rb + j;
        int n = by * 128 + wc * 64 + ni * 16 + cl;
        float v = acc[mi][ni][j];
        if constexpr (OP == HOP_QKV) {
          u16 hi = f2bf(v); u16 lo = f2bf(v - bf2f(hi));
          int sel = n >> 10, nn = n & 1023;
          if (sel == 0) {
            p.D0h[(size_t)m * DM + nn] = hi; p.D0l[(size_t)m * DM + nn] = lo;
          } else if (sel == 1) {
            p.D1h[(size_t)m * DM + nn] = hi; p.D1l[(size_t)m * DM + nn] = lo;
          } else {
            size_t idx = (size_t)((m >> 9) * 8 + (nn >> 7)) * 65536 + (size_t)(nn & 127) * 512 + (m & 511);
            p.D2h[idx] = hi; p.D2l[idx] = lo;
          }
        } else if constexpr (OP == HOP_SCORES) {
          p.Cf[(size_t)z * 262144 + (size_t)m * 512 + n] = v;
        } else if constexpr (OP == HOP_PV) {
          u16 hi = f2bf(v); u16 lo = f2bf(v - bf2f(hi));
          size_t idx = (size_t)(z >> 3) * 524288 + (size_t)m * 1024 + (size_t)(z & 7) * 128 + n;
          p.D0h[idx] = hi; p.D0l[idx] = lo;
        } else { // HOP_PROJ
          size_t idx = (size_t)m * 1024 + n;
          p.Cf[idx] = v + p.bias[n] + p.resid[idx] + p.pos[(size_t)(m & 511) * 1024 + n];
        }
      }
}

// ---------------- bf16 MFMA 128x128 TN GEMM, 2-phase dbuf, 16-expert merged (MoE) ----------------
constexpr int OP_MOE1 = 0; // gathered A rows (joblist -> xlnb[2*TOK]), bf16 C=relu(acc+b1)
constexpr int OP_MOE2 = 1; // contiguous padded A rows, bf16 C=acc+b2

struct GemmArgs {
  const u16* A; const u16* B; void* C;
  const float* b1a; const float* b1b;   // per-half bias arrays (8 experts each)
  const int* joblist; const int* seg;   // seg[0..16]
  int lda, ldb, K;
};

template<int OP>
__launch_bounds__(256)
__global__ void gemm_k(GemmArgs p) {
  int bid = blockIdx.x;
  int xcd = bid & 7, slot = bid >> 3;
  int bx, by;
  if constexpr (OP == OP_MOE1) {
    by = xcd * 4 + (slot & 3);        // grid 4608
    bx = slot >> 2;
  } else {
    bx = xcd * 18 + (slot >> 3);      // grid 1152
    by = slot & 7;
  }
  int r0g = bx * 128;
  if (r0g >= p.seg[16]) return;
  int z = 0;
  #pragma unroll
  for (int e = 1; e < 16; ++e) z += (r0g >= p.seg[e]) ? 1 : 0;
  const u16* Bbase = p.B + (size_t)z * 4194304;
  const float* bias = (z < 8) ? p.b1a + (size_t)z * (OP == OP_MOE1 ? FF : DM)
                              : p.b1b + (size_t)(z - 8) * (OP == OP_MOE1 ? FF : DM);

  __shared__ __align__(16) u16 As[2 * 4096];
  __shared__ __align__(16) u16 Bs[2 * 4096];

  int tid = threadIdx.x;
  int lane = tid & 63, wid = tid >> 6;

  int srow = wid * 16 + (lane >> 2);
  int skoff = (lane & 3) * 8;

  const u16 *aptr0, *aptr1;
  if constexpr (OP == OP_MOE1) {
    int j0 = p.joblist[r0g + srow];
    int j1 = p.joblist[r0g + 64 + srow];
    aptr0 = p.A + (size_t)(j0 < 0 ? 0 : j0) * p.lda + skoff;
    aptr1 = p.A + (size_t)(j1 < 0 ? 0 : j1) * p.lda + skoff;
  } else {
    aptr0 = p.A + (size_t)(r0g + srow) * p.lda + skoff;
    aptr1 = p.A + (size_t)(r0g + 64 + srow) * p.lda + skoff;
  }
  const u16* bptr0 = Bbase + (size_t)(by * 128 + srow) * p.ldb + skoff;
  const u16* bptr1 = Bbase + (size_t)(by * 128 + 64 + srow) * p.ldb + skoff;

  int lo0 = (wid * 16) * 32;
  int lo1 = ((wid + 4) * 16) * 32;

  int wr = wid >> 1, wc = wid & 1;
  int fm = lane & 15;
  int fk = (lane >> 4) * 8;

  f32x4 acc[4][4] = {};
  int nt = p.K >> 5;

  gl_lds16(aptr0, &As[lo0]); gl_lds16(aptr1, &As[lo1]);
  gl_lds16(bptr0, &Bs[lo0]); gl_lds16(bptr1, &Bs[lo1]);
  __syncthreads();

  int cur = 0;
  for (int t = 0; t < nt; ++t) {
    if (t + 1 < nt) {
      int nxt = (cur ^ 1) * 4096;
      int k0 = (t + 1) * 32;
      gl_lds16(aptr0 + k0, &As[nxt + lo0]); gl_lds16(aptr1 + k0, &As[nxt + lo1]);
      gl_lds16(bptr0 + k0, &Bs[nxt + lo0]); gl_lds16(bptr1 + k0, &Bs[nxt + lo1]);
    }
    int cb = cur * 4096;
    bf16x8 af[4], bfr[4];
    #pragma unroll
    for (int i = 0; i < 4; ++i) {
      af[i]  = *(const bf16x8*)&As[cb + (wr * 64 + i * 16 + fm) * 32 + fk];
      bfr[i] = *(const bf16x8*)&Bs[cb + (wc * 64 + i * 16 + fm) * 32 + fk];
    }
    #pragma unroll
    for (int mi = 0; mi < 4; ++mi)
      #pragma unroll
      for (int ni = 0; ni < 4; ++ni)
        acc[mi][ni] = __builtin_amdgcn_mfma_f32_16x16x32_bf16(af[mi], bfr[ni], acc[mi][ni], 0, 0, 0);
    __syncthreads();
    cur ^= 1;
  }

  int rb = (lane >> 4) * 4;
  int cl = lane & 15;
  #pragma unroll
  for (int mi = 0; mi < 4; ++mi)
    #pragma unroll
    for (int ni = 0; ni < 4; ++ni)
      #pragma unroll
      for (int j = 0; j < 4; ++j) {
        int m = r0g + wr * 64 + mi * 16 + rb + j;
        int n = by * 128 + wc * 64 + ni * 16 + cl;
        float v = acc[mi][ni][j] + bias[n];
        if constexpr (OP == OP_MOE1) {
          v = v > 0.f ? v : 0.f;
          ((u16*)p.C)[(size_t)m * FF + n] = f2bf(v);
        } else {
          ((u16*)p.C)[(size_t)m * DM + n] = f2bf(v);
        }
      }
}

// ---------------- MoE bookkeeping (16-expert merged) ----------------
__global__ void k_moe_init(int* cnt, int* cnt2, int* joblist) {
  int i = blockIdx.x * 256 + threadIdx.x;
  if (i < JOBCAP) joblist[i] = -1;
  if (i < 16) { cnt[i] = 0; cnt2[i] = 0; }
}
__global__ void k_moe_count(const int* __restrict__ topidx, int* __restrict__ cnt) {
  int t = blockIdx.x * 256 + threadIdx.x;     // global token 0..2*TOK
  if (t >= 2 * TOK) return;
  int lo = (t >= TOK) ? 8 : 0;
  atomicAdd(&cnt[topidx[t * 2] + lo], 1);
  atomicAdd(&cnt[topidx[t * 2 + 1] + lo], 1);
}
__global__ void k_moe_offsets(const int* __restrict__ cnt, int* __restrict__ seg) {
  if (threadIdx.x == 0) {
    int o = 0;
    for (int e = 0; e < 16; e++) { seg[e] = o; o += (cnt[e] + 127) & ~127; }
    seg[16] = o;
  }
}
__global__ void k_moe_scatter(const int* __restrict__ topidx, int* __restrict__ cnt2,
                              const int* __restrict__ seg, int* __restrict__ joblist,
                              int* __restrict__ tokpos) {
  int t = blockIdx.x * 256 + threadIdx.x;
  if (t >= 2 * TOK) return;
  int lo = (t >= TOK) ? 8 : 0;
  #pragma unroll
  for (int s = 0; s < 2; s++) {
    int e = topidx[t * 2 + s] + lo;
    int p = atomicAdd(&cnt2[e], 1);
    int pos = seg[e] + p;
    joblist[pos] = t;                 // global row into xlnb[2*TOK]
    tokpos[t * 2 + s] = pos;
  }
}
__global__ void k_combine(const u16* __restrict__ y, const float* __restrict__ gates,
                          const int* __restrict__ tokpos, float* __restrict__ out) {
  int t = blockIdx.x, tid = threadIdx.x;
  int p0 = tokpos[t * 2], p1 = tokpos[t * 2 + 1];
  float g0 = gates[t * 2], g1 = gates[t * 2 + 1];
  ushort4 a = ((const ushort4*)(y + (size_t)p0 * DM))[tid];
  ushort4 b = ((const ushort4*)(y + (size_t)p1 * DM))[tid];
  float4 o;
  o.x = g0 * bf2f(a.x) + g1 * bf2f(b.x);
  o.y = g0 * bf2f(a.y) + g1 * bf2f(b.y);
  o.z = g0 * bf2f(a.z) + g1 * bf2f(b.z);
  o.w = g0 * bf2f(a.w) + g1 * bf2f(b.w);
  ((float4*)(out + (size_t)t * DM))[tid] = o;
}

// ---------------- feature mean (two-stage) + classifier ----------------
__global__ void k_feat1(const float* __restrict__ second, float* __restrict__ part) {
  int b = blockIdx.x, c = blockIdx.y, tid = threadIdx.x;
  const float* p = second + ((size_t)b * SEQ + (size_t)c * 64) * DM;
  float4 s = {0.f, 0.f, 0.f, 0.f};
  for (int j = 0; j < 64; ++j) {
    float4 v = ((const float4*)(p + (size_t)j * DM))[tid];
    s.x += v.x; s.y += v.y; s.z += v.z; s.w += v.w;
  }
  ((float4*)(part + (size_t)(b * 8 + c) * DM))[tid] = s;
}
__global__ void k_feat2(const float* __restrict__ part, float* __restrict__ feat) {
  int i = blockIdx.x * 256 + threadIdx.x;
  int b = i >> 10, d = i & 1023;
  float s = 0.f;
  #pragma unroll
  for (int c = 0; c < 8; ++c) s += part[(size_t)(b * 8 + c) * DM + d];
  feat[i] = s * (1.f / SEQ);
}
__global__ void k_cls(const float* __restrict__ feat, const float* __restrict__ Wc,
                      const float* __restrict__ bc, float* __restrict__ cls) {
  int o = blockIdx.x; int b = o / 10, n = o % 10; int l = threadIdx.x;
  float s = 0.f;
  for (int d = l; d < DM; d += 64) s += feat[b * DM + d] * Wc[(size_t)d * 10 + n];
  for (int off = 32; off; off >>= 1) s += __shfl_down(s, off);
  if (l == 0) cls[o] = s + bc[n];
}

// ---------------- launch ----------------
extern "C" void kernel_launch(void* const* d_in, const int* in_sizes, int n_in,
                              void* d_out, int out_size, void* d_ws, size_t ws_size,
                              hipStream_t stream) {
  const int*   ids    = (const int*)d_in[0];
  const float* emb    = (const float*)d_in[2];
  const float* pos    = (const float*)d_in[3];
  const float* Wq     = (const float*)d_in[4];
  const float* Wk     = (const float*)d_in[5];
  const float* Wv     = (const float*)d_in[6];
  const float* Wo     = (const float*)d_in[7];
  const float* bo     = (const float*)d_in[8];
  const float* g1     = (const float*)d_in[9];
  const float* be1    = (const float*)d_in[10];
  const float* g2     = (const float*)d_in[11];
  const float* be2    = (const float*)d_in[12];
  const float* g3     = (const float*)d_in[13];
  const float* be3    = (const float*)d_in[14];
  const float* Wr1    = (const float*)d_in[15];
  const float* br1    = (const float*)d_in[16];
  const float* Wn1    = (const float*)d_in[17];
  const float* bn1    = (const float*)d_in[18];
  const float* W1a    = (const float*)d_in[19];
  const float* b1a    = (const float*)d_in[20];
  const float* W2a    = (const float*)d_in[21];
  const float* b2a    = (const float*)d_in[22];
  const float* Wr2    = (const float*)d_in[23];
  const float* br2    = (const float*)d_in[24];
  const float* Wn2    = (const float*)d_in[25];
  const float* bn2    = (const float*)d_in[26];
  const float* W1b    = (const float*)d_in[27];
  const float* b1b    = (const float*)d_in[28];
  const float* W2b    = (const float*)d_in[29];
  const float* b2b    = (const float*)d_in[30];
  const float* noise1 = (const float*)d_in[31];
  const float* noise2 = (const float*)d_in[32];
  const float* Wc     = (const float*)d_in[33];
  const float* bc     = (const float*)d_in[34];

  char* wsp = (char*)d_ws; size_t off = 0;
  auto alloc = [&](size_t bytes) -> void* {
    void* p = wsp + off; off += (bytes + 255) & ~(size_t)255; return p;
  };
  char*  G     = (char*)alloc(360710144);              // phase-overlaid big region (344MB)
  float* x     = (float*)alloc((size_t)TOK * DM * 4);
  float* x2    = (float*)alloc((size_t)TOK * DM * 4);
  u16*   xlnb  = (u16*)alloc((size_t)2 * TOK * DM * 2);   // both layers' LN
  float* gates  = (float*)alloc(2 * TOK * 2 * 4);
  int*   topidx = (int*)alloc(2 * TOK * 2 * 4);
  int*   cnt    = (int*)alloc(16 * 4);
  int*   cnt2   = (int*)alloc(16 * 4);
  int*   seg    = (int*)alloc(24 * 4);
  int*   joblist= (int*)alloc(JOBCAP * 4);
  int*   tokpos = (int*)alloc(2 * TOK * 2 * 4);
  float* fpart  = (float*)alloc(64 * DM * 4);
  (void)ws_size; (void)in_sizes; (void)n_in; (void)out_size;

  // attention-phase views (~164MB of G)
  u16* WQKVTh = (u16*)(G + 0);
  u16* WQKVTl = (u16*)(G + 6291456);
  u16* WOTh   = (u16*)(G + 12582912);
  u16* WOTl   = (u16*)(G + 14680064);
  u16* XLNH   = (u16*)(G + 16777216);
  u16* XLNL   = (u16*)(G + 25165824);
  u16* QH     = (u16*)(G + 33554432);
  u16* QL     = (u16*)(G + 41943040);
  u16* KH     = (u16*)(G + 50331648);
  u16* KL     = (u16*)(G + 58720256);
  u16* VTh    = (u16*)(G + 67108864);
  u16* VTl    = (u16*)(G + 75497472);
  u16* OH     = (u16*)(G + 83886080);
  u16* OL     = (u16*)(G + 92274688);
  float* SC   = (float*)(G + 100663296);  // [64][512][512] f32 -> att hi/lo in place
  // moe-phase views (G; attention buffers dead by then)
  u16*   H    = (u16*)(G + 0);            // [18432][4096] bf16 (151MB)
  u16*   Y    = (u16*)(G + 150994944);    // [18432][1024] bf16 (37.7MB)
  u16*   WBUF = (u16*)(G + 226492416);    // 16 experts' weights bf16 (128MB)

  float* out_first  = (float*)d_out;
  float* out_second = out_first + (size_t)TOK * DM;
  float* feat       = out_first + (size_t)2 * TOK * DM;
  float* cls        = feat + 8 * DM;

  dim3 tb(32, 8);
  // ---- attention phase: split-bf16 fused 3-term ----
  hipLaunchKernelGGL(k_tcvt_split4, dim3(32, 32, 4), tb, 0, stream, Wq, Wk, Wv, Wo,
                     WQKVTh, WQKVTl, WOTh, WOTl);
  hipLaunchKernelGGL(k_embed, dim3(TOK), dim3(256), 0, stream, ids, emb, x);
  hipLaunchKernelGGL(k_ln2, dim3(TOK), dim3(256), 0, stream, x, g1, be1, XLNH, XLNL);

  GemmHArgs qa{};
  qa.Ah = XLNH; qa.Al = XLNL; qa.Bh = WQKVTh; qa.Bl = WQKVTl;
  qa.D0h = QH; qa.D0l = QL; qa.D1h = KH; qa.D1l = KL; qa.D2h = VTh; qa.D2l = VTl;
  qa.lda = DM; qa.ldb = DM; qa.K = DM;
  hipLaunchKernelGGL(gemm_h<HOP_QKV>, dim3(768), dim3(256), 0, stream, qa);

  GemmHArgs sa{};
  sa.Ah = QH; sa.Al = QL; sa.Bh = KH; sa.Bl = KL; sa.Cf = SC;
  sa.lda = DM; sa.ldb = DM; sa.K = HD;
  hipLaunchKernelGGL(gemm_h<HOP_SCORES>, dim3(640), dim3(256), 0, stream, sa);
  hipLaunchKernelGGL(k_softmax_h, dim3(SEQ, 64), dim3(256), 0, stream, SC);

  GemmHArgs pa{};
  pa.Ah = (const u16*)SC; pa.Bh = VTh; pa.Bl = VTl;
  pa.D0h = OH; pa.D0l = OL;
  pa.lda = 1024; pa.ldb = 512; pa.K = SEQ;
  hipLaunchKernelGGL(gemm_h<HOP_PV>, dim3(4, 1, 64), dim3(256), 0, stream, pa);

  GemmHArgs pj{};
  pj.Ah = OH; pj.Al = OL; pj.Bh = WOTh; pj.Bl = WOTl; pj.Cf = x2;
  pj.bias = bo; pj.resid = x; pj.pos = pos;
  pj.lda = DM; pj.ldb = DM; pj.K = DM;
  hipLaunchKernelGGL(gemm_h<HOP_PROJ>, dim3(256), dim3(256), 0, stream, pj);

  // ---- MoE phase: both layers merged into one 16-expert batch ----
  hipLaunchKernelGGL(k_lnrouter, dim3(TOK), dim3(256), 0, stream, x2, g2, be2,
                     Wr1, br1, Wn1, bn1, noise1, xlnb, gates, topidx);
  hipLaunchKernelGGL(k_lnrouter, dim3(TOK), dim3(256), 0, stream, x2, g3, be3,
                     Wr2, br2, Wn2, bn2, noise2, xlnb + (size_t)TOK * DM,
                     gates + (size_t)TOK * 2, topidx + (size_t)TOK * 2);
  hipLaunchKernelGGL(k_moe_init, dim3(72), dim3(256), 0, stream, cnt, cnt2, joblist);
  hipLaunchKernelGGL(k_moe_count, dim3(32), dim3(256), 0, stream, topidx, cnt);
  hipLaunchKernelGGL(k_moe_offsets, dim3(1), dim3(64), 0, stream, cnt, seg);
  hipLaunchKernelGGL(k_moe_scatter, dim3(32), dim3(256), 0, stream, topidx, cnt2, seg, joblist, tokpos);

  hipLaunchKernelGGL(k_tcvt64, dim3(16, 64, 16), tb, 0, stream, W1a, W1b, WBUF, DM, FF);
  GemmArgs m1{};
  m1.A = xlnb; m1.B = WBUF; m1.C = H; m1.b1a = b1a; m1.b1b = b1b;
  m1.joblist = joblist; m1.seg = seg;
  m1.lda = DM; m1.ldb = DM; m1.K = DM;
  hipLaunchKernelGGL(gemm_k<OP_MOE1>, dim3(4608), dim3(256), 0, stream, m1);

  hipLaunchKernelGGL(k_tcvt64, dim3(64, 16, 16), tb, 0, stream, W2a, W2b, WBUF, FF, DM);
  GemmArgs m2{};
  m2.A = H; m2.B = WBUF; m2.C = Y; m2.b1a = b2a; m2.b1b = b2b;
  m2.joblist = joblist; m2.seg = seg;
  m2.lda = FF; m2.ldb = FF; m2.K = FF;
  hipLaunchKernelGGL(gemm_k<OP_MOE2>, dim3(1152), dim3(256), 0, stream, m2);

  hipLaunchKernelGGL(k_combine, dim3(TOK), dim3(256), 0, stream, Y, gates, tokpos, out_first);
  hipLaunchKernelGGL(k_combine, dim3(TOK), dim3(256), 0, stream, Y,
                     gates + (size_t)TOK * 2, tokpos + (size_t)TOK * 2, out_second);

  hipLaunchKernelGGL(k_feat1, dim3(8, 8), dim3(256), 0, stream, out_second, fpart);
  hipLaunchKernelGGL(k_feat2, dim3(32), dim3(256), 0, stream, fpart, feat);
  hipLaunchKernelGGL(k_cls, dim3(80), dim3(64), 0, stream, feat, Wc, bc, cls);
}